// Round 5
// baseline (1153.590 us; speedup 1.0000x reference)
//
#include <hip/hip_runtime.h>

#define N_NODES 50000
#define N_EDGES 800000

typedef __attribute__((ext_vector_type(8))) short short8;
typedef __attribute__((ext_vector_type(4))) float floatx4;

__device__ __forceinline__ short f2bf(float f) {
  unsigned int u = __builtin_bit_cast(unsigned int, f);
  unsigned int r = (u + 0x7FFFu + ((u >> 16) & 1u)) >> 16;
  return (short)r;
}
// pack two f32 -> packed bf16 dword (lo = a, hi = b), RTNE
__device__ __forceinline__ unsigned int pack2bf(float a, float b) {
  unsigned int ua = __builtin_bit_cast(unsigned int, a);
  unsigned int ub = __builtin_bit_cast(unsigned int, b);
  ua = (ua + 0x7FFFu + ((ua >> 16) & 1u)) >> 16;
  ub = (ub + 0x7FFFu + ((ub >> 16) & 1u)) & 0xFFFF0000u;
  return ua | ub;
}
__device__ __forceinline__ float fsilu(float v) {
  float e = __builtin_amdgcn_exp2f(v * -1.442695041f);
  return v * __builtin_amdgcn_rcpf(1.f + e);
}

// h (f32) -> h_bf (bf16)
__global__ void prep_h(const float* __restrict__ h, short* __restrict__ h_bf) {
  int id = blockIdx.x * 256 + threadIdx.x;
  const float4 v = *(const float4*)(h + (size_t)id * 4);
  short4 t;
  t.x = f2bf(v.x); t.y = f2bf(v.y); t.z = f2bf(v.z); t.w = f2bf(v.w);
  *(short4*)(h_bf + (size_t)id * 4) = t;
}

// f32 weights [K,128] -> bf16 MFMA frag order (doubles as A-frag of W^T)
__global__ void prep_weights(const float* __restrict__ eW1, const float* __restrict__ eW2,
                             const float* __restrict__ nW1, const float* __restrict__ nW2,
                             short* __restrict__ W1f, short* __restrict__ W2f,
                             short* __restrict__ N1f, short* __restrict__ N2f) {
  int id = blockIdx.x * 256 + threadIdx.x;   // 0..12287
  const float* src; short* dst; int ch;
  if (id < 4096)       { src = eW1; dst = W1f; ch = id; }
  else if (id < 6144)  { src = eW2; dst = W2f; ch = id - 4096; }
  else if (id < 10240) { src = nW1; dst = N1f; ch = id - 6144; }
  else                 { src = nW2; dst = N2f; ch = id - 10240; }
  int kt = ch >> 9;
  int c  = (ch >> 6) & 7;
  int l  = ch & 63;
  int q = l >> 4, n = l & 15;
  int k0 = kt * 32 + q * 8;
  int col = c * 16 + n;
  short tmp[8];
#pragma unroll
  for (int j = 0; j < 8; ++j) tmp[j] = f2bf(src[(k0 + j) * 128 + col]);
#pragma unroll
  for (int j = 0; j < 8; ++j) dst[ch * 8 + j] = tmp[j];
}

// ---- CSR build: histogram of destination rows
__global__ void hist_kernel(const int* __restrict__ idx, int* __restrict__ cnt) {
  int gid = blockIdx.x * 256 + threadIdx.x;
  atomicAdd(&cnt[idx[gid]], 1);
}

// exclusive scan of cnt[50000] -> ctmp (single block, 1024 threads)
__global__ void scan_kernel(const int* __restrict__ cnt, int* __restrict__ ctmp) {
  __shared__ int wsum[16];
  const int t = threadIdx.x;
  const int base = t * 49;
  int s = 0;
  for (int k = 0; k < 49; ++k) {
    int i = base + k;
    if (i < N_NODES) s += cnt[i];
  }
  // wave-inclusive scan of per-thread sums
  int val = s;
  const int lane = t & 63;
#pragma unroll
  for (int off = 1; off < 64; off <<= 1) {
    int tmp = __shfl_up(val, off, 64);
    if (lane >= off) val += tmp;
  }
  if (lane == 63) wsum[t >> 6] = val;
  __syncthreads();
  if (t == 0) {
    int run = 0;
    for (int i = 0; i < 16; ++i) { int x = wsum[i]; wsum[i] = run; run += x; }
  }
  __syncthreads();
  int excl = val - s + wsum[t >> 6];   // exclusive prefix at this thread's chunk
  int run = excl;
  for (int k = 0; k < 49; ++k) {
    int i = base + k;
    if (i < N_NODES) { int c = cnt[i]; ctmp[i] = run; run += c; }
  }
}

// place edges into sorted order (by destination row)
__global__ void place_kernel(const int* __restrict__ idx, int* __restrict__ ctmp,
                             int* __restrict__ srow, int* __restrict__ scol) {
  int gid = blockIdx.x * 256 + threadIdx.x;
  int r = idx[gid];
  int c = idx[N_EDGES + gid];
  int p = atomicAdd(&ctmp[r], 1);
  srow[p] = r;
  scol[p] = c;
}

// Edge kernel (transposed GEMMs, sorted edges, segmented LDS reduction).
// 64 sorted edges/block, 512 threads (8 waves). Wave w: et=w&3 (edge 16-tile),
// cg=w>>2 (channel half). Lane(q,n): edge erow=et*16+n, channels (cg*4+cc)*16+4q+j.
// Post-GEMM: edge_feat accumulated into segAgg[seg][128] f32 (ds_add_f32,
// overlays dead X/M1), one pk-bf16 atomic per (block, distinct dest node).
__global__ void __launch_bounds__(512, 6) edge_kernel(
    const short* __restrict__ h_bf,
    const int* __restrict__ srow, const int* __restrict__ scol,
    const short* __restrict__ W1f, const short* __restrict__ W2f,
    const float* __restrict__ eb1, const float* __restrict__ eb2,
    const float* __restrict__ aW, const float* __restrict__ ab,
    unsigned short* __restrict__ agg) {
  __shared__ __align__(16) short Smem[16896];   // X[64][264] / M1[64][136] / segAgg f32[64][128]
  __shared__ float patt[64][2];
  __shared__ int urow[64];
  __shared__ unsigned char segid_sh[64];
  __shared__ int nseg_sh;
  const int tid = threadIdx.x;
  const int e0 = blockIdx.x * 64;

  // wave 0: segment ids over the block's 64 sorted destination rows
  if (tid < 64) {
    int r = srow[e0 + tid];
    int rprev = __shfl_up(r, 1, 64);
    int flag = (tid == 0) || (r != rprev);
    unsigned long long mask = __ballot(flag);
    int seg = __popcll(mask & ((2ull << tid) - 1ull)) - 1;
    segid_sh[tid] = (unsigned char)seg;
    if (flag) urow[seg] = r;
    if (tid == 0) nseg_sh = (int)__popcll(mask);
  }
  // gather x = [h[row] | h[col]] -> X rows of 256 bf16 (stride 264)
#pragma unroll
  for (int i = 0; i < 4; ++i) {
    int id = i * 512 + tid;
    int e = id >> 5, ch = id & 31;
    int node = (ch < 16) ? srow[e0 + e] : scol[e0 + e];
    *(uint4*)(Smem + e * 264 + ch * 8) =
        *(const uint4*)(h_bf + (size_t)node * 128 + (ch & 15) * 8);
  }
  __syncthreads();
  const int w = tid >> 6, lane = tid & 63, q = lane >> 4, n = lane & 15;
  const int et = w & 3, cg = w >> 2;
  const int erow = et * 16 + n;

  // ---- layer 1 (transposed): C^T = W1^T @ X^T
  floatx4 acc[4];
#pragma unroll
  for (int cc = 0; cc < 4; ++cc) acc[cc] = (floatx4){0.f, 0.f, 0.f, 0.f};
  {
    const short* Brow = Smem + erow * 264 + q * 8;
    const short8* A = (const short8*)W1f;
#pragma unroll
    for (int kt = 0; kt < 8; ++kt) {
      short8 b = *(const short8*)(Brow + kt * 32);
#pragma unroll
      for (int cc = 0; cc < 4; ++cc) {
        short8 a = A[kt * 512 + (cg * 4 + cc) * 64 + lane];
        acc[cc] = __builtin_amdgcn_mfma_f32_16x16x32_bf16(a, b, acc[cc], 0, 0, 0);
      }
    }
  }
  unsigned int m1p[4][2];
#pragma unroll
  for (int cc = 0; cc < 4; ++cc) {
    int ct = cg * 4 + cc;
    const float4 b1 = *(const float4*)(eb1 + ct * 16 + 4 * q);
    float v0 = fsilu(acc[cc][0] + b1.x);
    float v1 = fsilu(acc[cc][1] + b1.y);
    float v2 = fsilu(acc[cc][2] + b1.z);
    float v3 = fsilu(acc[cc][3] + b1.w);
    m1p[cc][0] = pack2bf(v0, v1);
    m1p[cc][1] = pack2bf(v2, v3);
  }
  __syncthreads();
#pragma unroll
  for (int cc = 0; cc < 4; ++cc) {
    int ct = cg * 4 + cc;
    *(uint2*)(Smem + erow * 136 + ct * 16 + 4 * q) = *(uint2*)m1p[cc];
  }
  __syncthreads();

  // ---- layer 2 (transposed): C^T = W2^T @ M1^T
  floatx4 acc2[4];
#pragma unroll
  for (int cc = 0; cc < 4; ++cc) acc2[cc] = (floatx4){0.f, 0.f, 0.f, 0.f};
  {
    const short* Brow = Smem + erow * 136 + q * 8;
    const short8* A = (const short8*)W2f;
#pragma unroll
    for (int kt = 0; kt < 4; ++kt) {
      short8 b = *(const short8*)(Brow + kt * 32);
#pragma unroll
      for (int cc = 0; cc < 4; ++cc) {
        short8 a = A[kt * 512 + (cg * 4 + cc) * 64 + lane];
        acc2[cc] = __builtin_amdgcn_mfma_f32_16x16x32_bf16(a, b, acc2[cc], 0, 0, 0);
      }
    }
  }
  // ---- silu + attention partial dot (this wave's 64 channels of edge erow)
  float sil[4][4];
  float p = 0.f;
#pragma unroll
  for (int cc = 0; cc < 4; ++cc) {
    int ct = cg * 4 + cc;
    const float4 b2 = *(const float4*)(eb2 + ct * 16 + 4 * q);
    const float4 av = *(const float4*)(aW + ct * 16 + 4 * q);
#pragma unroll
    for (int j = 0; j < 4; ++j) {
      float v = fsilu(acc2[cc][j] + ((const float*)&b2)[j]);
      sil[cc][j] = v;
      p += v * ((const float*)&av)[j];
    }
  }
  p += __shfl_xor(p, 16, 64);
  p += __shfl_xor(p, 32, 64);
  if (q == 0) patt[erow][cg] = p;
  __syncthreads();   // M1 reads done (Smem reusable), patt ready

  float s = patt[erow][0] + patt[erow][1] + ab[0];
  float att = 0.01f * __builtin_amdgcn_rcpf(1.f + __builtin_amdgcn_exp2f(-1.442695041f * s));
  const int myseg = segid_sh[erow];

  // ---- zero segAgg (f32[64][128] overlays Smem)
  float* segAgg = (float*)Smem;
  {
    float4 z = {0.f, 0.f, 0.f, 0.f};
    float4* za = (float4*)segAgg;
#pragma unroll
    for (int i = 0; i < 4; ++i) za[tid * 4 + i] = z;
  }
  __syncthreads();
  // ---- segmented accumulate: edge_feat*att into segAgg[seg][ch]
#pragma unroll
  for (int cc = 0; cc < 4; ++cc) {
    int ct = cg * 4 + cc;
#pragma unroll
    for (int j = 0; j < 4; ++j) {
      atomicAdd(&segAgg[myseg * 128 + ct * 16 + 4 * q + j], sil[cc][j] * att);
    }
  }
  __syncthreads();
  // ---- flush: one pk-bf16 atomic per (segment, column-pair)
  const int nseg = nseg_sh;
  for (int s0 = 0; s0 < nseg; s0 += 8) {
    int sg = s0 + (tid >> 6);
    if (sg < nseg) {
      int ch = (tid & 63) * 2;
      unsigned int u = pack2bf(segAgg[sg * 128 + ch], segAgg[sg * 128 + ch + 1]);
      unsigned short* addr = agg + (size_t)urow[sg] * 128 + ch;
      asm volatile("global_atomic_pk_add_bf16 %0, %1, off" :: "v"(addr), "v"(u) : "memory");
    }
  }
  asm volatile("s_waitcnt vmcnt(0)" ::: "memory");
}

// Node kernel: 64 nodes/block. z=[h_bf, agg(bf16)] [64][264] in LDS; M1 overlays.
__global__ void __launch_bounds__(256) node_kernel(
    const float* __restrict__ h, const short* __restrict__ h_bf,
    const short* __restrict__ agg,
    const short* __restrict__ N1f, const short* __restrict__ N2f,
    const float* __restrict__ nb1, const float* __restrict__ nb2,
    float* __restrict__ out) {
  __shared__ __align__(16) short Smem[16896];
  const int tid = threadIdx.x;
  const int n0 = blockIdx.x * 64;
#pragma unroll
  for (int i = 0; i < 8; ++i) {
    int id = i * 256 + tid;
    int r = id >> 5, ch = id & 31;
    int rg = n0 + r;
    if (rg >= N_NODES) rg = N_NODES - 1;
    const short* src = (ch < 16) ? (h_bf + (size_t)rg * 128 + ch * 8)
                                 : (agg + (size_t)rg * 128 + (ch - 16) * 8);
    *(uint4*)(Smem + r * 264 + ch * 8) = *(const uint4*)src;
  }
  __syncthreads();
  const int w = tid >> 6, lane = tid & 63, q = lane >> 4, n = lane & 15;

  floatx4 acc[8];
#pragma unroll
  for (int c = 0; c < 8; ++c) acc[c] = (floatx4){0.f, 0.f, 0.f, 0.f};
  {
    const short* Arow = Smem + (16 * w + n) * 264 + q * 8;
    const short8* B = (const short8*)N1f + lane;
#pragma unroll
    for (int kt = 0; kt < 8; ++kt) {
      short8 a = *(const short8*)(Arow + kt * 32);
#pragma unroll
      for (int c = 0; c < 8; ++c) {
        short8 b = B[kt * 512 + c * 64];
        acc[c] = __builtin_amdgcn_mfma_f32_16x16x32_bf16(a, b, acc[c], 0, 0, 0);
      }
    }
  }
  __syncthreads();
#pragma unroll
  for (int c = 0; c < 8; ++c) {
    float b1 = nb1[c * 16 + n];
#pragma unroll
    for (int j = 0; j < 4; ++j) {
      float v = fsilu(acc[c][j] + b1);
      Smem[(16 * w + q * 4 + j) * 136 + c * 16 + n] = f2bf(v);
    }
  }
  __syncthreads();

  floatx4 acc2[8];
#pragma unroll
  for (int c = 0; c < 8; ++c) acc2[c] = (floatx4){0.f, 0.f, 0.f, 0.f};
  {
    const short* Arow = Smem + (16 * w + n) * 136 + q * 8;
    const short8* B = (const short8*)N2f + lane;
#pragma unroll
    for (int kt = 0; kt < 4; ++kt) {
      short8 a = *(const short8*)(Arow + kt * 32);
#pragma unroll
      for (int c = 0; c < 8; ++c) {
        short8 b = B[kt * 512 + c * 64];
        acc2[c] = __builtin_amdgcn_mfma_f32_16x16x32_bf16(a, b, acc2[c], 0, 0, 0);
      }
    }
  }
#pragma unroll
  for (int c = 0; c < 8; ++c) {
    int col = c * 16 + n;
    float b2 = nb2[col];
#pragma unroll
    for (int j = 0; j < 4; ++j) {
      int rg = n0 + 16 * w + q * 4 + j;
      if (rg < N_NODES) {
        size_t off = (size_t)rg * 128 + col;
        out[off] = acc2[c][j] + b2 + h[off];
      }
    }
  }
}

extern "C" void kernel_launch(void* const* d_in, const int* in_sizes, int n_in,
                              void* d_out, int out_size, void* d_ws, size_t ws_size,
                              hipStream_t stream) {
  (void)in_sizes; (void)n_in; (void)out_size; (void)ws_size;
  const float* h   = (const float*)d_in[0];
  const int*   idx = (const int*)d_in[1];
  const float* eW1 = (const float*)d_in[2];
  const float* eb1 = (const float*)d_in[3];
  const float* eW2 = (const float*)d_in[4];
  const float* eb2 = (const float*)d_in[5];
  const float* aW  = (const float*)d_in[6];
  const float* ab  = (const float*)d_in[7];
  const float* nW1 = (const float*)d_in[8];
  const float* nb1 = (const float*)d_in[9];
  const float* nW2 = (const float*)d_in[10];
  const float* nb2 = (const float*)d_in[11];
  float* out = (float*)d_out;

  // ws layout
  char* wp = (char*)d_ws;
  unsigned short* agg = (unsigned short*)wp;                 wp += (size_t)N_NODES * 128 * 2;  // 12.8 MB
  short* h_bf = (short*)wp;                                  wp += (size_t)N_NODES * 128 * 2;  // 12.8 MB
  short* W1f = (short*)wp;                                   wp += 32768 * 2;
  short* W2f = (short*)wp;                                   wp += 16384 * 2;
  short* N1f = (short*)wp;                                   wp += 32768 * 2;
  short* N2f = (short*)wp;                                   wp += 16384 * 2;
  int* cnt  = (int*)wp;                                      wp += N_NODES * 4;
  int* ctmp = (int*)wp;                                      wp += N_NODES * 4;
  int* srow = (int*)wp;                                      wp += N_EDGES * 4;
  int* scol = (int*)wp;                                      wp += N_EDGES * 4;

  hipMemsetAsync(agg, 0, (size_t)N_NODES * 128 * 2, stream);
  hipMemsetAsync(cnt, 0, N_NODES * 4, stream);
  prep_h<<<N_NODES * 128 / 4 / 256, 256, 0, stream>>>(h, h_bf);
  prep_weights<<<48, 256, 0, stream>>>(eW1, eW2, nW1, nW2, W1f, W2f, N1f, N2f);
  hist_kernel<<<N_EDGES / 256, 256, 0, stream>>>(idx, cnt);
  scan_kernel<<<1, 1024, 0, stream>>>(cnt, ctmp);
  place_kernel<<<N_EDGES / 256, 256, 0, stream>>>(idx, ctmp, srow, scol);
  edge_kernel<<<N_EDGES / 64, 512, 0, stream>>>(h_bf, srow, scol, W1f, W2f,
                                                eb1, eb2, aW, ab, agg);
  node_kernel<<<(N_NODES + 63) / 64, 256, 0, stream>>>(h, h_bf, (const short*)agg,
                                                       N1f, N2f, nb1, nb2, out);
}

// Round 6
// 558.912 us; speedup vs baseline: 2.0640x; 2.0640x over previous
//
#include <hip/hip_runtime.h>

#define N_NODES 50000
#define N_EDGES 800000

typedef __attribute__((ext_vector_type(8))) short short8;
typedef __attribute__((ext_vector_type(4))) float floatx4;

__device__ __forceinline__ short f2bf(float f) {
  unsigned int u = __builtin_bit_cast(unsigned int, f);
  unsigned int r = (u + 0x7FFFu + ((u >> 16) & 1u)) >> 16;
  return (short)r;
}
// pack two f32 -> packed bf16 dword (lo = a, hi = b), RTNE
__device__ __forceinline__ unsigned int pack2bf(float a, float b) {
  unsigned int ua = __builtin_bit_cast(unsigned int, a);
  unsigned int ub = __builtin_bit_cast(unsigned int, b);
  ua = (ua + 0x7FFFu + ((ua >> 16) & 1u)) >> 16;
  ub = (ub + 0x7FFFu + ((ub >> 16) & 1u)) & 0xFFFF0000u;
  return ua | ub;
}
__device__ __forceinline__ float fsilu(float v) {
  float e = __builtin_amdgcn_exp2f(v * -1.442695041f);
  return v * __builtin_amdgcn_rcpf(1.f + e);
}

// h (f32) -> h_bf (bf16)
__global__ void prep_h(const float* __restrict__ h, short* __restrict__ h_bf) {
  int id = blockIdx.x * 256 + threadIdx.x;
  const float4 v = *(const float4*)(h + (size_t)id * 4);
  short4 t;
  t.x = f2bf(v.x); t.y = f2bf(v.y); t.z = f2bf(v.z); t.w = f2bf(v.w);
  *(short4*)(h_bf + (size_t)id * 4) = t;
}

// f32 weights [K,128] -> bf16 MFMA frag order (doubles as A-frag of W^T)
__global__ void prep_weights(const float* __restrict__ eW1, const float* __restrict__ eW2,
                             const float* __restrict__ nW1, const float* __restrict__ nW2,
                             short* __restrict__ W1f, short* __restrict__ W2f,
                             short* __restrict__ N1f, short* __restrict__ N2f) {
  int id = blockIdx.x * 256 + threadIdx.x;   // 0..12287
  const float* src; short* dst; int ch;
  if (id < 4096)       { src = eW1; dst = W1f; ch = id; }
  else if (id < 6144)  { src = eW2; dst = W2f; ch = id - 4096; }
  else if (id < 10240) { src = nW1; dst = N1f; ch = id - 6144; }
  else                 { src = nW2; dst = N2f; ch = id - 10240; }
  int kt = ch >> 9;
  int c  = (ch >> 6) & 7;
  int l  = ch & 63;
  int q = l >> 4, n = l & 15;
  int k0 = kt * 32 + q * 8;
  int col = c * 16 + n;
  short tmp[8];
#pragma unroll
  for (int j = 0; j < 8; ++j) tmp[j] = f2bf(src[(k0 + j) * 128 + col]);
#pragma unroll
  for (int j = 0; j < 8; ++j) dst[ch * 8 + j] = tmp[j];
}

// ---- CSR build: histogram of destination rows
__global__ void hist_kernel(const int* __restrict__ idx, int* __restrict__ cnt) {
  int gid = blockIdx.x * 256 + threadIdx.x;
  atomicAdd(&cnt[idx[gid]], 1);
}

// exclusive scan of cnt[50000] -> ctmp (single block, 1024 threads)
__global__ void scan_kernel(const int* __restrict__ cnt, int* __restrict__ ctmp) {
  __shared__ int wsum[16];
  const int t = threadIdx.x;
  const int base = t * 49;
  int s = 0;
  for (int k = 0; k < 49; ++k) {
    int i = base + k;
    if (i < N_NODES) s += cnt[i];
  }
  int val = s;
  const int lane = t & 63;
#pragma unroll
  for (int off = 1; off < 64; off <<= 1) {
    int tmp = __shfl_up(val, off, 64);
    if (lane >= off) val += tmp;
  }
  if (lane == 63) wsum[t >> 6] = val;
  __syncthreads();
  if (t == 0) {
    int run = 0;
    for (int i = 0; i < 16; ++i) { int x = wsum[i]; wsum[i] = run; run += x; }
  }
  __syncthreads();
  int excl = val - s + wsum[t >> 6];
  int run = excl;
  for (int k = 0; k < 49; ++k) {
    int i = base + k;
    if (i < N_NODES) { int c = cnt[i]; ctmp[i] = run; run += c; }
  }
}

// place edges into sorted order (by destination row), one 8B scatter
__global__ void place_kernel(const int* __restrict__ idx, int* __restrict__ ctmp,
                             int2* __restrict__ sedge) {
  int gid = blockIdx.x * 256 + threadIdx.x;
  int r = idx[gid];
  int c = idx[N_EDGES + gid];
  int p = atomicAdd(&ctmp[r], 1);
  sedge[p] = make_int2(r, c);
}

// Edge kernel: transposed GEMMs, sorted edges, shuffle-segmented reduction.
// 64 sorted edges/block, 512 threads (8 waves). Wave w: et=w&3 (edge 16-tile),
// cg=w>>2 (channel half). Lane(q,n): edge erow=et*16+n, channels (cg*4+cc)*16+4q+j.
// Aggregation: ballot run-flags over sorted rows -> segmented inclusive scan via
// shfl_up along n -> only run-TAIL lanes issue pk-bf16 atomics (run totals).
__global__ void __launch_bounds__(512, 6) edge_kernel(
    const short* __restrict__ h_bf, const int2* __restrict__ sedge,
    const short* __restrict__ W1f, const short* __restrict__ W2f,
    const float* __restrict__ eb1, const float* __restrict__ eb2,
    const float* __restrict__ aW, const float* __restrict__ ab,
    unsigned short* __restrict__ agg) {
  __shared__ __align__(16) short Smem[16896];   // X[64][264] overlaid by M1[64][136]
  __shared__ float patt[64][2];
  __shared__ int rowid[64];
  const int tid = threadIdx.x;
  const int e0 = blockIdx.x * 64;
  if (tid < 64) rowid[tid] = sedge[e0 + tid].x;
  // gather x = [h[row] | h[col]] -> X rows of 256 bf16 (stride 264)
#pragma unroll
  for (int i = 0; i < 4; ++i) {
    int id = i * 512 + tid;
    int e = id >> 5, ch = id & 31;
    int node = (ch < 16) ? sedge[e0 + e].x : sedge[e0 + e].y;
    *(uint4*)(Smem + e * 264 + ch * 8) =
        *(const uint4*)(h_bf + (size_t)node * 128 + (ch & 15) * 8);
  }
  __syncthreads();
  const int w = tid >> 6, lane = tid & 63, q = lane >> 4, n = lane & 15;
  const int et = w & 3, cg = w >> 2;
  const int erow = et * 16 + n;

  // ---- layer 1 (transposed): C^T = W1^T @ X^T
  floatx4 acc[4];
#pragma unroll
  for (int cc = 0; cc < 4; ++cc) acc[cc] = (floatx4){0.f, 0.f, 0.f, 0.f};
  {
    const short* Brow = Smem + erow * 264 + q * 8;
    const short8* A = (const short8*)W1f;
#pragma unroll
    for (int kt = 0; kt < 8; ++kt) {
      short8 b = *(const short8*)(Brow + kt * 32);
#pragma unroll
      for (int cc = 0; cc < 4; ++cc) {
        short8 a = A[kt * 512 + (cg * 4 + cc) * 64 + lane];
        acc[cc] = __builtin_amdgcn_mfma_f32_16x16x32_bf16(a, b, acc[cc], 0, 0, 0);
      }
    }
  }
  unsigned int m1p[4][2];
#pragma unroll
  for (int cc = 0; cc < 4; ++cc) {
    int ct = cg * 4 + cc;
    const float4 b1 = *(const float4*)(eb1 + ct * 16 + 4 * q);
    float v0 = fsilu(acc[cc][0] + b1.x);
    float v1 = fsilu(acc[cc][1] + b1.y);
    float v2 = fsilu(acc[cc][2] + b1.z);
    float v3 = fsilu(acc[cc][3] + b1.w);
    m1p[cc][0] = pack2bf(v0, v1);
    m1p[cc][1] = pack2bf(v2, v3);
  }
  __syncthreads();
#pragma unroll
  for (int cc = 0; cc < 4; ++cc) {
    int ct = cg * 4 + cc;
    *(uint2*)(Smem + erow * 136 + ct * 16 + 4 * q) = *(uint2*)m1p[cc];
  }
  __syncthreads();

  // ---- layer 2 (transposed): C^T = W2^T @ M1^T
  floatx4 acc2[4];
#pragma unroll
  for (int cc = 0; cc < 4; ++cc) acc2[cc] = (floatx4){0.f, 0.f, 0.f, 0.f};
  {
    const short* Brow = Smem + erow * 136 + q * 8;
    const short8* A = (const short8*)W2f;
#pragma unroll
    for (int kt = 0; kt < 4; ++kt) {
      short8 b = *(const short8*)(Brow + kt * 32);
#pragma unroll
      for (int cc = 0; cc < 4; ++cc) {
        short8 a = A[kt * 512 + (cg * 4 + cc) * 64 + lane];
        acc2[cc] = __builtin_amdgcn_mfma_f32_16x16x32_bf16(a, b, acc2[cc], 0, 0, 0);
      }
    }
  }
  // ---- silu + attention partial dot (this wave's 64 channels of edge erow)
  float sil[4][4];
  float p = 0.f;
#pragma unroll
  for (int cc = 0; cc < 4; ++cc) {
    int ct = cg * 4 + cc;
    const float4 b2 = *(const float4*)(eb2 + ct * 16 + 4 * q);
    const float4 av = *(const float4*)(aW + ct * 16 + 4 * q);
#pragma unroll
    for (int j = 0; j < 4; ++j) {
      float v = fsilu(acc2[cc][j] + ((const float*)&b2)[j]);
      sil[cc][j] = v;
      p += v * ((const float*)&av)[j];
    }
  }
  p += __shfl_xor(p, 16, 64);
  p += __shfl_xor(p, 32, 64);
  if (q == 0) patt[erow][cg] = p;
  __syncthreads();

  // gate (fold /NORM_FACTOR), scale this edge's features
  float s = patt[erow][0] + patt[erow][1] + ab[0];
  float att = 0.01f * __builtin_amdgcn_rcpf(1.f + __builtin_amdgcn_exp2f(-1.442695041f * s));
#pragma unroll
  for (int cc = 0; cc < 4; ++cc)
#pragma unroll
    for (int j = 0; j < 4; ++j) sil[cc][j] *= att;

  // ---- segmented reduction over sorted-row runs along n (16 edges/tile)
  const int myrow = rowid[erow];
  const int prevrow = (n == 0) ? -1 : rowid[erow - 1];
  const bool head = (n == 0) || (myrow != prevrow);
  const unsigned long long m = __ballot(head);
  const unsigned long long lower = (lane == 63) ? ~0ull : ((2ull << lane) - 1ull);
  const int headpos = 63 - __builtin_clzll(m & lower);
  const int hd = lane - headpos;                       // distance to my run's head
  const bool tail = (n == 15) || (((m >> (lane + 1)) & 1ull) != 0);
#pragma unroll
  for (int d = 1; d < 16; d <<= 1) {
    bool take = (d <= hd);
#pragma unroll
    for (int cc = 0; cc < 4; ++cc)
#pragma unroll
      for (int j = 0; j < 4; ++j) {
        float t = __shfl_up(sil[cc][j], d, 64);
        if (take) sil[cc][j] += t;
      }
  }
  // ---- run tails flush run totals: 8 pk-bf16 atomics per tail lane
  if (tail) {
    unsigned short* base = agg + (size_t)myrow * 128;
#pragma unroll
    for (int cc = 0; cc < 4; ++cc) {
      int colb = (cg * 4 + cc) * 16 + 4 * q;
      unsigned int u0 = pack2bf(sil[cc][0], sil[cc][1]);
      unsigned int u1 = pack2bf(sil[cc][2], sil[cc][3]);
      asm volatile("global_atomic_pk_add_bf16 %0, %1, off" :: "v"(base + colb), "v"(u0) : "memory");
      asm volatile("global_atomic_pk_add_bf16 %0, %1, off" :: "v"(base + colb + 2), "v"(u1) : "memory");
    }
  }
  asm volatile("s_waitcnt vmcnt(0)" ::: "memory");   // drain untracked asm atomics
}

// Node kernel: 64 nodes/block. z=[h_bf, agg(bf16)] [64][264] in LDS; M1 overlays.
__global__ void __launch_bounds__(256) node_kernel(
    const float* __restrict__ h, const short* __restrict__ h_bf,
    const short* __restrict__ agg,
    const short* __restrict__ N1f, const short* __restrict__ N2f,
    const float* __restrict__ nb1, const float* __restrict__ nb2,
    float* __restrict__ out) {
  __shared__ __align__(16) short Smem[16896];
  const int tid = threadIdx.x;
  const int n0 = blockIdx.x * 64;
#pragma unroll
  for (int i = 0; i < 8; ++i) {
    int id = i * 256 + tid;
    int r = id >> 5, ch = id & 31;
    int rg = n0 + r;
    if (rg >= N_NODES) rg = N_NODES - 1;
    const short* src = (ch < 16) ? (h_bf + (size_t)rg * 128 + ch * 8)
                                 : (agg + (size_t)rg * 128 + (ch - 16) * 8);
    *(uint4*)(Smem + r * 264 + ch * 8) = *(const uint4*)src;
  }
  __syncthreads();
  const int w = tid >> 6, lane = tid & 63, q = lane >> 4, n = lane & 15;

  floatx4 acc[8];
#pragma unroll
  for (int c = 0; c < 8; ++c) acc[c] = (floatx4){0.f, 0.f, 0.f, 0.f};
  {
    const short* Arow = Smem + (16 * w + n) * 264 + q * 8;
    const short8* B = (const short8*)N1f + lane;
#pragma unroll
    for (int kt = 0; kt < 8; ++kt) {
      short8 a = *(const short8*)(Arow + kt * 32);
#pragma unroll
      for (int c = 0; c < 8; ++c) {
        short8 b = B[kt * 512 + c * 64];
        acc[c] = __builtin_amdgcn_mfma_f32_16x16x32_bf16(a, b, acc[c], 0, 0, 0);
      }
    }
  }
  __syncthreads();
#pragma unroll
  for (int c = 0; c < 8; ++c) {
    float b1 = nb1[c * 16 + n];
#pragma unroll
    for (int j = 0; j < 4; ++j) {
      float v = fsilu(acc[c][j] + b1);
      Smem[(16 * w + q * 4 + j) * 136 + c * 16 + n] = f2bf(v);
    }
  }
  __syncthreads();

  floatx4 acc2[8];
#pragma unroll
  for (int c = 0; c < 8; ++c) acc2[c] = (floatx4){0.f, 0.f, 0.f, 0.f};
  {
    const short* Arow = Smem + (16 * w + n) * 136 + q * 8;
    const short8* B = (const short8*)N2f + lane;
#pragma unroll
    for (int kt = 0; kt < 4; ++kt) {
      short8 a = *(const short8*)(Arow + kt * 32);
#pragma unroll
      for (int c = 0; c < 8; ++c) {
        short8 b = B[kt * 512 + c * 64];
        acc2[c] = __builtin_amdgcn_mfma_f32_16x16x32_bf16(a, b, acc2[c], 0, 0, 0);
      }
    }
  }
#pragma unroll
  for (int c = 0; c < 8; ++c) {
    int col = c * 16 + n;
    float b2 = nb2[col];
#pragma unroll
    for (int j = 0; j < 4; ++j) {
      int rg = n0 + 16 * w + q * 4 + j;
      if (rg < N_NODES) {
        size_t off = (size_t)rg * 128 + col;
        out[off] = acc2[c][j] + b2 + h[off];
      }
    }
  }
}

extern "C" void kernel_launch(void* const* d_in, const int* in_sizes, int n_in,
                              void* d_out, int out_size, void* d_ws, size_t ws_size,
                              hipStream_t stream) {
  (void)in_sizes; (void)n_in; (void)out_size; (void)ws_size;
  const float* h   = (const float*)d_in[0];
  const int*   idx = (const int*)d_in[1];
  const float* eW1 = (const float*)d_in[2];
  const float* eb1 = (const float*)d_in[3];
  const float* eW2 = (const float*)d_in[4];
  const float* eb2 = (const float*)d_in[5];
  const float* aW  = (const float*)d_in[6];
  const float* ab  = (const float*)d_in[7];
  const float* nW1 = (const float*)d_in[8];
  const float* nb1 = (const float*)d_in[9];
  const float* nW2 = (const float*)d_in[10];
  const float* nb2 = (const float*)d_in[11];
  float* out = (float*)d_out;

  // ws layout
  char* wp = (char*)d_ws;
  unsigned short* agg = (unsigned short*)wp;  wp += (size_t)N_NODES * 128 * 2;  // 12.8 MB
  short* h_bf = (short*)wp;                   wp += (size_t)N_NODES * 128 * 2;  // 12.8 MB
  short* W1f = (short*)wp;                    wp += 32768 * 2;
  short* W2f = (short*)wp;                    wp += 16384 * 2;
  short* N1f = (short*)wp;                    wp += 32768 * 2;
  short* N2f = (short*)wp;                    wp += 16384 * 2;
  int* cnt  = (int*)wp;                       wp += N_NODES * 4;
  int* ctmp = (int*)wp;                       wp += N_NODES * 4;
  int2* sedge = (int2*)wp;                    wp += (size_t)N_EDGES * 8;

  hipMemsetAsync(agg, 0, (size_t)N_NODES * 128 * 2, stream);
  hipMemsetAsync(cnt, 0, N_NODES * 4, stream);
  prep_h<<<N_NODES * 128 / 4 / 256, 256, 0, stream>>>(h, h_bf);
  prep_weights<<<48, 256, 0, stream>>>(eW1, eW2, nW1, nW2, W1f, W2f, N1f, N2f);
  hist_kernel<<<N_EDGES / 256, 256, 0, stream>>>(idx, cnt);
  scan_kernel<<<1, 1024, 0, stream>>>(cnt, ctmp);
  place_kernel<<<N_EDGES / 256, 256, 0, stream>>>(idx, ctmp, sedge);
  edge_kernel<<<N_EDGES / 64, 512, 0, stream>>>(h_bf, sedge, W1f, W2f,
                                                eb1, eb2, aW, ab, agg);
  node_kernel<<<(N_NODES + 63) / 64, 256, 0, stream>>>(h, h_bf, (const short*)agg,
                                                       N1f, N2f, nb1, nb2, out);
}

// Round 7
// 502.898 us; speedup vs baseline: 2.2939x; 1.1114x over previous
//
#include <hip/hip_runtime.h>

#define N_NODES 50000
#define N_EDGES 800000

typedef __attribute__((ext_vector_type(8))) short short8;
typedef __attribute__((ext_vector_type(4))) float floatx4;

__device__ __forceinline__ short f2bf(float f) {
  unsigned int u = __builtin_bit_cast(unsigned int, f);
  unsigned int r = (u + 0x7FFFu + ((u >> 16) & 1u)) >> 16;
  return (short)r;
}
// pack two f32 -> packed bf16 dword (lo = a, hi = b), RTNE
__device__ __forceinline__ unsigned int pack2bf(float a, float b) {
  unsigned int ua = __builtin_bit_cast(unsigned int, a);
  unsigned int ub = __builtin_bit_cast(unsigned int, b);
  ua = (ua + 0x7FFFu + ((ua >> 16) & 1u)) >> 16;
  ub = (ub + 0x7FFFu + ((ub >> 16) & 1u)) & 0xFFFF0000u;
  return ua | ub;
}
__device__ __forceinline__ float fsilu(float v) {
  float e = __builtin_amdgcn_exp2f(v * -1.442695041f);
  return v * __builtin_amdgcn_rcpf(1.f + e);
}

// h (f32) -> h_bf (bf16)
__global__ void prep_h(const float* __restrict__ h, short* __restrict__ h_bf) {
  int id = blockIdx.x * 256 + threadIdx.x;
  const float4 v = *(const float4*)(h + (size_t)id * 4);
  short4 t;
  t.x = f2bf(v.x); t.y = f2bf(v.y); t.z = f2bf(v.z); t.w = f2bf(v.w);
  *(short4*)(h_bf + (size_t)id * 4) = t;
}

// f32 weights [K,128] -> bf16 MFMA frag order (doubles as A-frag of W^T)
__global__ void prep_weights(const float* __restrict__ eW1, const float* __restrict__ eW2,
                             const float* __restrict__ nW1, const float* __restrict__ nW2,
                             short* __restrict__ W1f, short* __restrict__ W2f,
                             short* __restrict__ N1f, short* __restrict__ N2f) {
  int id = blockIdx.x * 256 + threadIdx.x;   // 0..12287
  const float* src; short* dst; int ch;
  if (id < 4096)       { src = eW1; dst = W1f; ch = id; }
  else if (id < 6144)  { src = eW2; dst = W2f; ch = id - 4096; }
  else if (id < 10240) { src = nW1; dst = N1f; ch = id - 6144; }
  else                 { src = nW2; dst = N2f; ch = id - 10240; }
  int kt = ch >> 9;
  int c  = (ch >> 6) & 7;
  int l  = ch & 63;
  int q = l >> 4, n = l & 15;
  int k0 = kt * 32 + q * 8;
  int col = c * 16 + n;
  short tmp[8];
#pragma unroll
  for (int j = 0; j < 8; ++j) tmp[j] = f2bf(src[(k0 + j) * 128 + col]);
#pragma unroll
  for (int j = 0; j < 8; ++j) dst[ch * 8 + j] = tmp[j];
}

// ---- CSR build: histogram of destination rows; atomic return = edge's rank
__global__ void hist_kernel(const int* __restrict__ idx, int* __restrict__ cnt,
                            int* __restrict__ rank) {
  int gid = blockIdx.x * 256 + threadIdx.x;
  rank[gid] = atomicAdd(&cnt[idx[gid]], 1);
}

// exclusive scan of cnt[50000] -> ctmp (single block, 1024 threads)
__global__ void scan_kernel(const int* __restrict__ cnt, int* __restrict__ ctmp) {
  __shared__ int wsum[16];
  const int t = threadIdx.x;
  const int base = t * 49;
  int s = 0;
  for (int k = 0; k < 49; ++k) {
    int i = base + k;
    if (i < N_NODES) s += cnt[i];
  }
  int val = s;
  const int lane = t & 63;
#pragma unroll
  for (int off = 1; off < 64; off <<= 1) {
    int tmp = __shfl_up(val, off, 64);
    if (lane >= off) val += tmp;
  }
  if (lane == 63) wsum[t >> 6] = val;
  __syncthreads();
  if (t == 0) {
    int run = 0;
    for (int i = 0; i < 16; ++i) { int x = wsum[i]; wsum[i] = run; run += x; }
  }
  __syncthreads();
  int excl = val - s + wsum[t >> 6];
  int run = excl;
  for (int k = 0; k < 49; ++k) {
    int i = base + k;
    if (i < N_NODES) { int c = cnt[i]; ctmp[i] = run; run += c; }
  }
}

// place edges into sorted order: p = row_base + precomputed rank (NO atomics)
__global__ void place_kernel(const int* __restrict__ idx, const int* __restrict__ ctmp,
                             const int* __restrict__ rank, int2* __restrict__ sedge) {
  int gid = blockIdx.x * 256 + threadIdx.x;
  int r = idx[gid];
  int c = idx[N_EDGES + gid];
  int p = ctmp[r] + rank[gid];
  sedge[p] = make_int2(r, c);
}

// Edge kernel: transposed GEMMs, sorted edges, shuffle-segmented reduction.
// 64 sorted edges/block, 512 threads (8 waves). Wave w: et=w&3 (edge 16-tile),
// cg=w>>2 (channel half). Lane(q,n): edge erow=et*16+n, channels (cg*4+cc)*16+4q+j.
// Aggregation: ballot run-flags over sorted rows -> segmented inclusive scan via
// shfl_up along n -> only run-TAIL lanes issue pk-bf16 atomics (run totals).
__global__ void __launch_bounds__(512, 6) edge_kernel(
    const short* __restrict__ h_bf, const int2* __restrict__ sedge,
    const short* __restrict__ W1f, const short* __restrict__ W2f,
    const float* __restrict__ eb1, const float* __restrict__ eb2,
    const float* __restrict__ aW, const float* __restrict__ ab,
    unsigned short* __restrict__ agg) {
  __shared__ __align__(16) short Smem[16896];   // X[64][264] overlaid by M1[64][136]
  __shared__ float patt[64][2];
  __shared__ int rowid[64];
  const int tid = threadIdx.x;
  const int e0 = blockIdx.x * 64;
  if (tid < 64) rowid[tid] = sedge[e0 + tid].x;
  // gather x = [h[row] | h[col]] -> X rows of 256 bf16 (stride 264)
#pragma unroll
  for (int i = 0; i < 4; ++i) {
    int id = i * 512 + tid;
    int e = id >> 5, ch = id & 31;
    int node = (ch < 16) ? sedge[e0 + e].x : sedge[e0 + e].y;
    *(uint4*)(Smem + e * 264 + ch * 8) =
        *(const uint4*)(h_bf + (size_t)node * 128 + (ch & 15) * 8);
  }
  __syncthreads();
  const int w = tid >> 6, lane = tid & 63, q = lane >> 4, n = lane & 15;
  const int et = w & 3, cg = w >> 2;
  const int erow = et * 16 + n;

  // ---- layer 1 (transposed): C^T = W1^T @ X^T
  floatx4 acc[4];
#pragma unroll
  for (int cc = 0; cc < 4; ++cc) acc[cc] = (floatx4){0.f, 0.f, 0.f, 0.f};
  {
    const short* Brow = Smem + erow * 264 + q * 8;
    const short8* A = (const short8*)W1f;
#pragma unroll
    for (int kt = 0; kt < 8; ++kt) {
      short8 b = *(const short8*)(Brow + kt * 32);
#pragma unroll
      for (int cc = 0; cc < 4; ++cc) {
        short8 a = A[kt * 512 + (cg * 4 + cc) * 64 + lane];
        acc[cc] = __builtin_amdgcn_mfma_f32_16x16x32_bf16(a, b, acc[cc], 0, 0, 0);
      }
    }
  }
  unsigned int m1p[4][2];
#pragma unroll
  for (int cc = 0; cc < 4; ++cc) {
    int ct = cg * 4 + cc;
    const float4 b1 = *(const float4*)(eb1 + ct * 16 + 4 * q);
    float v0 = fsilu(acc[cc][0] + b1.x);
    float v1 = fsilu(acc[cc][1] + b1.y);
    float v2 = fsilu(acc[cc][2] + b1.z);
    float v3 = fsilu(acc[cc][3] + b1.w);
    m1p[cc][0] = pack2bf(v0, v1);
    m1p[cc][1] = pack2bf(v2, v3);
  }
  __syncthreads();
#pragma unroll
  for (int cc = 0; cc < 4; ++cc) {
    int ct = cg * 4 + cc;
    *(uint2*)(Smem + erow * 136 + ct * 16 + 4 * q) = *(uint2*)m1p[cc];
  }
  __syncthreads();

  // ---- layer 2 (transposed): C^T = W2^T @ M1^T
  floatx4 acc2[4];
#pragma unroll
  for (int cc = 0; cc < 4; ++cc) acc2[cc] = (floatx4){0.f, 0.f, 0.f, 0.f};
  {
    const short* Brow = Smem + erow * 136 + q * 8;
    const short8* A = (const short8*)W2f;
#pragma unroll
    for (int kt = 0; kt < 4; ++kt) {
      short8 b = *(const short8*)(Brow + kt * 32);
#pragma unroll
      for (int cc = 0; cc < 4; ++cc) {
        short8 a = A[kt * 512 + (cg * 4 + cc) * 64 + lane];
        acc2[cc] = __builtin_amdgcn_mfma_f32_16x16x32_bf16(a, b, acc2[cc], 0, 0, 0);
      }
    }
  }
  // ---- silu + attention partial dot (this wave's 64 channels of edge erow)
  float sil[4][4];
  float p = 0.f;
#pragma unroll
  for (int cc = 0; cc < 4; ++cc) {
    int ct = cg * 4 + cc;
    const float4 b2 = *(const float4*)(eb2 + ct * 16 + 4 * q);
    const float4 av = *(const float4*)(aW + ct * 16 + 4 * q);
#pragma unroll
    for (int j = 0; j < 4; ++j) {
      float v = fsilu(acc2[cc][j] + ((const float*)&b2)[j]);
      sil[cc][j] = v;
      p += v * ((const float*)&av)[j];
    }
  }
  p += __shfl_xor(p, 16, 64);
  p += __shfl_xor(p, 32, 64);
  if (q == 0) patt[erow][cg] = p;
  __syncthreads();

  // gate (fold /NORM_FACTOR), scale this edge's features
  float s = patt[erow][0] + patt[erow][1] + ab[0];
  float att = 0.01f * __builtin_amdgcn_rcpf(1.f + __builtin_amdgcn_exp2f(-1.442695041f * s));
#pragma unroll
  for (int cc = 0; cc < 4; ++cc)
#pragma unroll
    for (int j = 0; j < 4; ++j) sil[cc][j] *= att;

  // ---- segmented reduction over sorted-row runs along n (16 edges/tile)
  const int myrow = rowid[erow];
  const int prevrow = (n == 0) ? -1 : rowid[erow - 1];
  const bool head = (n == 0) || (myrow != prevrow);
  const unsigned long long m = __ballot(head);
  const unsigned long long lower = (lane == 63) ? ~0ull : ((2ull << lane) - 1ull);
  const int headpos = 63 - __builtin_clzll(m & lower);
  const int hd = lane - headpos;                       // distance to my run's head
  const bool tail = (n == 15) || (((m >> (lane + 1)) & 1ull) != 0);
#pragma unroll
  for (int d = 1; d < 16; d <<= 1) {
    bool take = (d <= hd);
#pragma unroll
    for (int cc = 0; cc < 4; ++cc)
#pragma unroll
      for (int j = 0; j < 4; ++j) {
        float t = __shfl_up(sil[cc][j], d, 64);
        if (take) sil[cc][j] += t;
      }
  }
  // ---- run tails flush run totals: 8 pk-bf16 atomics per tail lane
  if (tail) {
    unsigned short* base = agg + (size_t)myrow * 128;
#pragma unroll
    for (int cc = 0; cc < 4; ++cc) {
      int colb = (cg * 4 + cc) * 16 + 4 * q;
      unsigned int u0 = pack2bf(sil[cc][0], sil[cc][1]);
      unsigned int u1 = pack2bf(sil[cc][2], sil[cc][3]);
      asm volatile("global_atomic_pk_add_bf16 %0, %1, off" :: "v"(base + colb), "v"(u0) : "memory");
      asm volatile("global_atomic_pk_add_bf16 %0, %1, off" :: "v"(base + colb + 2), "v"(u1) : "memory");
    }
  }
  asm volatile("s_waitcnt vmcnt(0)" ::: "memory");   // drain untracked asm atomics
}

// Node kernel (transposed, 512 threads): 64 nodes/block, 8 waves.
// Wave w: et=w&3 (node 16-tile), cg=w>>2 (channel half). Lane(q,n): node
// et*16+n, channels (cg*4+cc)*16+4q+j (consecutive -> float4 epilogue).
__global__ void __launch_bounds__(512, 6) node_kernel(
    const float* __restrict__ h, const short* __restrict__ h_bf,
    const short* __restrict__ agg,
    const short* __restrict__ N1f, const short* __restrict__ N2f,
    const float* __restrict__ nb1, const float* __restrict__ nb2,
    float* __restrict__ out) {
  __shared__ __align__(16) short Smem[16896];   // Z[64][264] overlaid by M1[64][136]
  const int tid = threadIdx.x;
  const int n0 = blockIdx.x * 64;
#pragma unroll
  for (int i = 0; i < 4; ++i) {
    int id = i * 512 + tid;
    int r = id >> 5, ch = id & 31;
    int rg = n0 + r;
    if (rg >= N_NODES) rg = N_NODES - 1;
    const short* src = (ch < 16) ? (h_bf + (size_t)rg * 128 + ch * 8)
                                 : (agg + (size_t)rg * 128 + (ch - 16) * 8);
    *(uint4*)(Smem + r * 264 + ch * 8) = *(const uint4*)src;
  }
  __syncthreads();
  const int w = tid >> 6, lane = tid & 63, q = lane >> 4, n = lane & 15;
  const int et = w & 3, cg = w >> 2;
  const int erow = et * 16 + n;

  // ---- layer 1 (transposed): C^T = N1^T @ Z^T
  floatx4 acc[4];
#pragma unroll
  for (int cc = 0; cc < 4; ++cc) acc[cc] = (floatx4){0.f, 0.f, 0.f, 0.f};
  {
    const short* Brow = Smem + erow * 264 + q * 8;
    const short8* A = (const short8*)N1f;
#pragma unroll
    for (int kt = 0; kt < 8; ++kt) {
      short8 b = *(const short8*)(Brow + kt * 32);
#pragma unroll
      for (int cc = 0; cc < 4; ++cc) {
        short8 a = A[kt * 512 + (cg * 4 + cc) * 64 + lane];
        acc[cc] = __builtin_amdgcn_mfma_f32_16x16x32_bf16(a, b, acc[cc], 0, 0, 0);
      }
    }
  }
  unsigned int m1p[4][2];
#pragma unroll
  for (int cc = 0; cc < 4; ++cc) {
    int ct = cg * 4 + cc;
    const float4 b1 = *(const float4*)(nb1 + ct * 16 + 4 * q);
    float v0 = fsilu(acc[cc][0] + b1.x);
    float v1 = fsilu(acc[cc][1] + b1.y);
    float v2 = fsilu(acc[cc][2] + b1.z);
    float v3 = fsilu(acc[cc][3] + b1.w);
    m1p[cc][0] = pack2bf(v0, v1);
    m1p[cc][1] = pack2bf(v2, v3);
  }
  __syncthreads();
#pragma unroll
  for (int cc = 0; cc < 4; ++cc) {
    int ct = cg * 4 + cc;
    *(uint2*)(Smem + erow * 136 + ct * 16 + 4 * q) = *(uint2*)m1p[cc];
  }
  __syncthreads();

  // ---- layer 2 (transposed): C^T = N2^T @ M1^T, float4 residual epilogue
  floatx4 acc2[4];
#pragma unroll
  for (int cc = 0; cc < 4; ++cc) acc2[cc] = (floatx4){0.f, 0.f, 0.f, 0.f};
  {
    const short* Brow = Smem + erow * 136 + q * 8;
    const short8* A = (const short8*)N2f;
#pragma unroll
    for (int kt = 0; kt < 4; ++kt) {
      short8 b = *(const short8*)(Brow + kt * 32);
#pragma unroll
      for (int cc = 0; cc < 4; ++cc) {
        short8 a = A[kt * 512 + (cg * 4 + cc) * 64 + lane];
        acc2[cc] = __builtin_amdgcn_mfma_f32_16x16x32_bf16(a, b, acc2[cc], 0, 0, 0);
      }
    }
  }
  const int node = n0 + erow;
  if (node < N_NODES) {
#pragma unroll
    for (int cc = 0; cc < 4; ++cc) {
      int col = (cg * 4 + cc) * 16 + 4 * q;
      const float4 b2 = *(const float4*)(nb2 + col);
      const float4 hr = *(const float4*)(h + (size_t)node * 128 + col);
      float4 o;
      o.x = acc2[cc][0] + b2.x + hr.x;
      o.y = acc2[cc][1] + b2.y + hr.y;
      o.z = acc2[cc][2] + b2.z + hr.z;
      o.w = acc2[cc][3] + b2.w + hr.w;
      *(float4*)(out + (size_t)node * 128 + col) = o;
    }
  }
}

extern "C" void kernel_launch(void* const* d_in, const int* in_sizes, int n_in,
                              void* d_out, int out_size, void* d_ws, size_t ws_size,
                              hipStream_t stream) {
  (void)in_sizes; (void)n_in; (void)out_size; (void)ws_size;
  const float* h   = (const float*)d_in[0];
  const int*   idx = (const int*)d_in[1];
  const float* eW1 = (const float*)d_in[2];
  const float* eb1 = (const float*)d_in[3];
  const float* eW2 = (const float*)d_in[4];
  const float* eb2 = (const float*)d_in[5];
  const float* aW  = (const float*)d_in[6];
  const float* ab  = (const float*)d_in[7];
  const float* nW1 = (const float*)d_in[8];
  const float* nb1 = (const float*)d_in[9];
  const float* nW2 = (const float*)d_in[10];
  const float* nb2 = (const float*)d_in[11];
  float* out = (float*)d_out;

  // ws layout
  char* wp = (char*)d_ws;
  unsigned short* agg = (unsigned short*)wp;  wp += (size_t)N_NODES * 128 * 2;  // 12.8 MB
  short* h_bf = (short*)wp;                   wp += (size_t)N_NODES * 128 * 2;  // 12.8 MB
  short* W1f = (short*)wp;                    wp += 32768 * 2;
  short* W2f = (short*)wp;                    wp += 16384 * 2;
  short* N1f = (short*)wp;                    wp += 32768 * 2;
  short* N2f = (short*)wp;                    wp += 16384 * 2;
  int* cnt  = (int*)wp;                       wp += N_NODES * 4;
  int* ctmp = (int*)wp;                       wp += N_NODES * 4;
  int* rank = (int*)wp;                       wp += (size_t)N_EDGES * 4;
  int2* sedge = (int2*)wp;                    wp += (size_t)N_EDGES * 8;

  hipMemsetAsync(agg, 0, (size_t)N_NODES * 128 * 2, stream);
  hipMemsetAsync(cnt, 0, N_NODES * 4, stream);
  prep_h<<<N_NODES * 128 / 4 / 256, 256, 0, stream>>>(h, h_bf);
  prep_weights<<<48, 256, 0, stream>>>(eW1, eW2, nW1, nW2, W1f, W2f, N1f, N2f);
  hist_kernel<<<N_EDGES / 256, 256, 0, stream>>>(idx, cnt, rank);
  scan_kernel<<<1, 1024, 0, stream>>>(cnt, ctmp);
  place_kernel<<<N_EDGES / 256, 256, 0, stream>>>(idx, ctmp, rank, sedge);
  edge_kernel<<<N_EDGES / 64, 512, 0, stream>>>(h_bf, sedge, W1f, W2f,
                                                eb1, eb2, aW, ab, agg);
  node_kernel<<<(N_NODES + 63) / 64, 512, 0, stream>>>(h, h_bf, (const short*)agg,
                                                       N1f, N2f, nb1, nb2, out);
}

// Round 8
// 407.321 us; speedup vs baseline: 2.8321x; 1.2346x over previous
//
#include <hip/hip_runtime.h>

#define N_NODES 50000
#define N_EDGES 800000

typedef __attribute__((ext_vector_type(8))) short short8;
typedef __attribute__((ext_vector_type(4))) float floatx4;

__device__ __forceinline__ short f2bf(float f) {
  unsigned int u = __builtin_bit_cast(unsigned int, f);
  unsigned int r = (u + 0x7FFFu + ((u >> 16) & 1u)) >> 16;
  return (short)r;
}
// pack two f32 -> packed bf16 dword (lo = a, hi = b), RTNE
__device__ __forceinline__ unsigned int pack2bf(float a, float b) {
  unsigned int ua = __builtin_bit_cast(unsigned int, a);
  unsigned int ub = __builtin_bit_cast(unsigned int, b);
  ua = (ua + 0x7FFFu + ((ua >> 16) & 1u)) >> 16;
  ub = (ub + 0x7FFFu + ((ub >> 16) & 1u)) & 0xFFFF0000u;
  return ua | ub;
}
__device__ __forceinline__ float bflo2f(unsigned int u) {
  return __builtin_bit_cast(float, u << 16);
}
__device__ __forceinline__ float bfhi2f(unsigned int u) {
  return __builtin_bit_cast(float, u & 0xFFFF0000u);
}
__device__ __forceinline__ float fsilu(float v) {
  float e = __builtin_amdgcn_exp2f(v * -1.442695041f);
  return v * __builtin_amdgcn_rcpf(1.f + e);
}

// f32 weights [K,128] -> bf16 MFMA frag order (doubles as A-frag of W^T)
__global__ void prep_weights(const float* __restrict__ eW1, const float* __restrict__ eW2,
                             const float* __restrict__ nW1, const float* __restrict__ nW2,
                             short* __restrict__ W1f, short* __restrict__ W2f,
                             short* __restrict__ N1f, short* __restrict__ N2f) {
  int id = blockIdx.x * 256 + threadIdx.x;   // 0..12287
  const float* src; short* dst; int ch;
  if (id < 4096)       { src = eW1; dst = W1f; ch = id; }
  else if (id < 6144)  { src = eW2; dst = W2f; ch = id - 4096; }
  else if (id < 10240) { src = nW1; dst = N1f; ch = id - 6144; }
  else                 { src = nW2; dst = N2f; ch = id - 10240; }
  int kt = ch >> 9;
  int c  = (ch >> 6) & 7;
  int l  = ch & 63;
  int q = l >> 4, n = l & 15;
  int k0 = kt * 32 + q * 8;
  int col = c * 16 + n;
  short tmp[8];
#pragma unroll
  for (int j = 0; j < 8; ++j) tmp[j] = f2bf(src[(k0 + j) * 128 + col]);
#pragma unroll
  for (int j = 0; j < 8; ++j) dst[ch * 8 + j] = tmp[j];
}

// Fused: h f32 -> h_bf bf16  AND  R = h @ eW1_top (row-side layer-1 partial),
// stored bf16. Transposed GEMM, 64 nodes/block, 512 threads.
__global__ void __launch_bounds__(512, 6) prep_hR(
    const float* __restrict__ h, const short* __restrict__ W1f,
    short* __restrict__ h_bf, short* __restrict__ Rb) {
  __shared__ __align__(16) short Z[64 * 136];
  const int tid = threadIdx.x;
  const int n0 = blockIdx.x * 64;
#pragma unroll
  for (int i = 0; i < 4; ++i) {
    int id = i * 512 + tid;
    int r = id >> 5, cq = id & 31;
    int rg = n0 + r; if (rg >= N_NODES) rg = N_NODES - 1;
    float4 v = *(const float4*)(h + (size_t)rg * 128 + cq * 4);
    short4 s;
    s.x = f2bf(v.x); s.y = f2bf(v.y); s.z = f2bf(v.z); s.w = f2bf(v.w);
    *(short4*)(h_bf + (size_t)rg * 128 + cq * 4) = s;
    *(short4*)(Z + r * 136 + cq * 4) = s;
  }
  __syncthreads();
  const int w = tid >> 6, lane = tid & 63, q = lane >> 4, n = lane & 15;
  const int et = w & 3, cg = w >> 2;
  const int erow = et * 16 + n;
  floatx4 acc[4];
#pragma unroll
  for (int cc = 0; cc < 4; ++cc) acc[cc] = (floatx4){0.f, 0.f, 0.f, 0.f};
  const short* Brow = Z + erow * 136 + q * 8;
  const short8* A = (const short8*)W1f;          // TOP half: kt 0..3
#pragma unroll
  for (int kt = 0; kt < 4; ++kt) {
    short8 b = *(const short8*)(Brow + kt * 32);
#pragma unroll
    for (int cc = 0; cc < 4; ++cc) {
      short8 a = A[kt * 512 + (cg * 4 + cc) * 64 + lane];
      acc[cc] = __builtin_amdgcn_mfma_f32_16x16x32_bf16(a, b, acc[cc], 0, 0, 0);
    }
  }
  const int node = n0 + erow;
  if (node < N_NODES) {
#pragma unroll
    for (int cc = 0; cc < 4; ++cc) {
      int col = (cg * 4 + cc) * 16 + 4 * q;
      uint2 u;
      u.x = pack2bf(acc[cc][0], acc[cc][1]);
      u.y = pack2bf(acc[cc][2], acc[cc][3]);
      *(uint2*)(Rb + (size_t)node * 128 + col) = u;
    }
  }
}

// ---- CSR build: histogram of destination rows; atomic return = edge's rank
__global__ void hist_kernel(const int* __restrict__ idx, int* __restrict__ cnt,
                            int* __restrict__ rank) {
  int gid = blockIdx.x * 256 + threadIdx.x;
  rank[gid] = atomicAdd(&cnt[idx[gid]], 1);
}

// two-level exclusive scan of cnt[50000] -> ctmp: 98 blocks x 512
__global__ void scan1(const int* __restrict__ cnt, int* __restrict__ bsum) {
  const int t = threadIdx.x;
  int i = blockIdx.x * 512 + t;
  int v = (i < N_NODES) ? cnt[i] : 0;
#pragma unroll
  for (int o = 1; o < 64; o <<= 1) v += __shfl_xor(v, o, 64);
  __shared__ int ws_[8];
  if ((t & 63) == 0) ws_[t >> 6] = v;
  __syncthreads();
  if (t == 0) {
    int s = 0;
#pragma unroll
    for (int k = 0; k < 8; ++k) s += ws_[k];
    bsum[blockIdx.x] = s;
  }
}

__global__ void scan2(const int* __restrict__ bsum, int* __restrict__ boff) {
  const int t = threadIdx.x;   // 128 threads
  int v = (t < 98) ? bsum[t] : 0;
  int incl = v;
  const int lane = t & 63;
#pragma unroll
  for (int o = 1; o < 64; o <<= 1) {
    int tmp = __shfl_up(incl, o, 64);
    if (lane >= o) incl += tmp;
  }
  __shared__ int s0;
  if (t == 63) s0 = incl;
  __syncthreads();
  if (t >= 64) incl += s0;
  boff[t] = incl - v;
}

__global__ void scan3(const int* __restrict__ cnt, const int* __restrict__ boff,
                      int* __restrict__ ctmp) {
  const int t = threadIdx.x;
  const int i = blockIdx.x * 512 + t;
  int v = (i < N_NODES) ? cnt[i] : 0;
  int incl = v;
  const int lane = t & 63;
#pragma unroll
  for (int o = 1; o < 64; o <<= 1) {
    int tmp = __shfl_up(incl, o, 64);
    if (lane >= o) incl += tmp;
  }
  __shared__ int wsum[8];
  if (lane == 63) wsum[t >> 6] = incl;
  __syncthreads();
  if (t == 0) {
    int run = 0;
#pragma unroll
    for (int k = 0; k < 8; ++k) { int x = wsum[k]; wsum[k] = run; run += x; }
  }
  __syncthreads();
  if (i < N_NODES) ctmp[i] = incl - v + wsum[t >> 6] + boff[blockIdx.x];
}

// place edges into sorted order: p = row_base + precomputed rank (NO atomics)
__global__ void place_kernel(const int* __restrict__ idx, const int* __restrict__ ctmp,
                             const int* __restrict__ rank, int2* __restrict__ sedge) {
  int gid = blockIdx.x * 256 + threadIdx.x;
  int r = idx[gid];
  int c = idx[N_EDGES + gid];
  int p = ctmp[r] + rank[gid];
  sedge[p] = make_int2(r, c);
}

// Edge kernel: layer-1 split (acc init = R[row]; B-frags direct from h_bf[col]).
// No gather phase, no X LDS, 2 barriers. 64 sorted edges/block, 512 threads.
// Wave w: et=w&3 (edge 16-tile), cg=w>>2 (channel half). Lane(q,n): edge
// erow=et*16+n, channels (cg*4+cc)*16+4q+j. Segmented shfl scan + tail atomics.
__global__ void __launch_bounds__(512, 6) edge_kernel(
    const short* __restrict__ h_bf, const short* __restrict__ Rb,
    const int2* __restrict__ sedge,
    const short* __restrict__ W1f, const short* __restrict__ W2f,
    const float* __restrict__ eb1, const float* __restrict__ eb2,
    const float* __restrict__ aW, const float* __restrict__ ab,
    unsigned short* __restrict__ agg) {
  __shared__ __align__(16) short M1[64 * 136];
  __shared__ float patt[64][2];
  const int tid = threadIdx.x;
  const int e0 = blockIdx.x * 64;
  const int w = tid >> 6, lane = tid & 63, q = lane >> 4, n = lane & 15;
  const int et = w & 3, cg = w >> 2;
  const int erow = et * 16 + n;
  const int2 ed = sedge[e0 + erow];
  const int myrow = ed.x;

  // ---- layer 1: acc init from R[row] (bf16), B direct from h_bf[col]
  floatx4 acc[4];
  {
    const short* Rrow = Rb + (size_t)myrow * 128;
#pragma unroll
    for (int cc = 0; cc < 4; ++cc) {
      uint2 u = *(const uint2*)(Rrow + (cg * 4 + cc) * 16 + 4 * q);
      acc[cc][0] = bflo2f(u.x); acc[cc][1] = bfhi2f(u.x);
      acc[cc][2] = bflo2f(u.y); acc[cc][3] = bfhi2f(u.y);
    }
  }
  {
    const short* Brow = h_bf + (size_t)ed.y * 128 + q * 8;
    const short8* A = (const short8*)W1f + 4 * 512;   // BOTTOM half (col side)
#pragma unroll
    for (int kt = 0; kt < 4; ++kt) {
      short8 b = *(const short8*)(Brow + kt * 32);
#pragma unroll
      for (int cc = 0; cc < 4; ++cc) {
        short8 a = A[kt * 512 + (cg * 4 + cc) * 64 + lane];
        acc[cc] = __builtin_amdgcn_mfma_f32_16x16x32_bf16(a, b, acc[cc], 0, 0, 0);
      }
    }
  }
  // silu + pack -> M1 (fresh LDS, no prior barrier needed)
#pragma unroll
  for (int cc = 0; cc < 4; ++cc) {
    int ct = cg * 4 + cc;
    const float4 b1 = *(const float4*)(eb1 + ct * 16 + 4 * q);
    uint2 u;
    u.x = pack2bf(fsilu(acc[cc][0] + b1.x), fsilu(acc[cc][1] + b1.y));
    u.y = pack2bf(fsilu(acc[cc][2] + b1.z), fsilu(acc[cc][3] + b1.w));
    *(uint2*)(M1 + erow * 136 + ct * 16 + 4 * q) = u;
  }
  __syncthreads();

  // ---- layer 2 (transposed): C^T = W2^T @ M1^T
  floatx4 acc2[4];
#pragma unroll
  for (int cc = 0; cc < 4; ++cc) acc2[cc] = (floatx4){0.f, 0.f, 0.f, 0.f};
  {
    const short* Brow = M1 + erow * 136 + q * 8;
    const short8* A = (const short8*)W2f;
#pragma unroll
    for (int kt = 0; kt < 4; ++kt) {
      short8 b = *(const short8*)(Brow + kt * 32);
#pragma unroll
      for (int cc = 0; cc < 4; ++cc) {
        short8 a = A[kt * 512 + (cg * 4 + cc) * 64 + lane];
        acc2[cc] = __builtin_amdgcn_mfma_f32_16x16x32_bf16(a, b, acc2[cc], 0, 0, 0);
      }
    }
  }
  // ---- silu + attention partial dot
  float sil[4][4];
  float p = 0.f;
#pragma unroll
  for (int cc = 0; cc < 4; ++cc) {
    int ct = cg * 4 + cc;
    const float4 b2 = *(const float4*)(eb2 + ct * 16 + 4 * q);
    const float4 av = *(const float4*)(aW + ct * 16 + 4 * q);
#pragma unroll
    for (int j = 0; j < 4; ++j) {
      float v = fsilu(acc2[cc][j] + ((const float*)&b2)[j]);
      sil[cc][j] = v;
      p += v * ((const float*)&av)[j];
    }
  }
  p += __shfl_xor(p, 16, 64);
  p += __shfl_xor(p, 32, 64);
  if (q == 0) patt[erow][cg] = p;
  __syncthreads();

  float s = patt[erow][0] + patt[erow][1] + ab[0];
  float att = 0.01f * __builtin_amdgcn_rcpf(1.f + __builtin_amdgcn_exp2f(-1.442695041f * s));
#pragma unroll
  for (int cc = 0; cc < 4; ++cc)
#pragma unroll
    for (int j = 0; j < 4; ++j) sil[cc][j] *= att;

  // ---- segmented reduction over sorted-row runs along n (16 edges/tile)
  const int prevrow = __shfl_up(myrow, 1, 64);
  const bool head = (n == 0) || (myrow != prevrow);
  const unsigned long long m = __ballot(head);
  const unsigned long long lower = (lane == 63) ? ~0ull : ((2ull << lane) - 1ull);
  const int headpos = 63 - __builtin_clzll(m & lower);
  const int hd = lane - headpos;
  const bool tail = (n == 15) || (((m >> (lane + 1)) & 1ull) != 0);
#pragma unroll
  for (int d = 1; d < 16; d <<= 1) {
    bool take = (d <= hd);
#pragma unroll
    for (int cc = 0; cc < 4; ++cc)
#pragma unroll
      for (int j = 0; j < 4; ++j) {
        float t = __shfl_up(sil[cc][j], d, 64);
        if (take) sil[cc][j] += t;
      }
  }
  // ---- run tails flush run totals: 8 pk-bf16 atomics per tail lane
  if (tail) {
    unsigned short* base = agg + (size_t)myrow * 128;
#pragma unroll
    for (int cc = 0; cc < 4; ++cc) {
      int colb = (cg * 4 + cc) * 16 + 4 * q;
      unsigned int u0 = pack2bf(sil[cc][0], sil[cc][1]);
      unsigned int u1 = pack2bf(sil[cc][2], sil[cc][3]);
      asm volatile("global_atomic_pk_add_bf16 %0, %1, off" :: "v"(base + colb), "v"(u0) : "memory");
      asm volatile("global_atomic_pk_add_bf16 %0, %1, off" :: "v"(base + colb + 2), "v"(u1) : "memory");
    }
  }
  asm volatile("s_waitcnt vmcnt(0)" ::: "memory");   // drain untracked asm atomics
}

// Node kernel (transposed, 512 threads): 64 nodes/block, 8 waves.
__global__ void __launch_bounds__(512, 6) node_kernel(
    const float* __restrict__ h, const short* __restrict__ h_bf,
    const short* __restrict__ agg,
    const short* __restrict__ N1f, const short* __restrict__ N2f,
    const float* __restrict__ nb1, const float* __restrict__ nb2,
    float* __restrict__ out) {
  __shared__ __align__(16) short Smem[16896];   // Z[64][264] overlaid by M1[64][136]
  const int tid = threadIdx.x;
  const int n0 = blockIdx.x * 64;
#pragma unroll
  for (int i = 0; i < 4; ++i) {
    int id = i * 512 + tid;
    int r = id >> 5, ch = id & 31;
    int rg = n0 + r;
    if (rg >= N_NODES) rg = N_NODES - 1;
    const short* src = (ch < 16) ? (h_bf + (size_t)rg * 128 + ch * 8)
                                 : (agg + (size_t)rg * 128 + (ch - 16) * 8);
    *(uint4*)(Smem + r * 264 + ch * 8) = *(const uint4*)src;
  }
  __syncthreads();
  const int w = tid >> 6, lane = tid & 63, q = lane >> 4, n = lane & 15;
  const int et = w & 3, cg = w >> 2;
  const int erow = et * 16 + n;

  floatx4 acc[4];
#pragma unroll
  for (int cc = 0; cc < 4; ++cc) acc[cc] = (floatx4){0.f, 0.f, 0.f, 0.f};
  {
    const short* Brow = Smem + erow * 264 + q * 8;
    const short8* A = (const short8*)N1f;
#pragma unroll
    for (int kt = 0; kt < 8; ++kt) {
      short8 b = *(const short8*)(Brow + kt * 32);
#pragma unroll
      for (int cc = 0; cc < 4; ++cc) {
        short8 a = A[kt * 512 + (cg * 4 + cc) * 64 + lane];
        acc[cc] = __builtin_amdgcn_mfma_f32_16x16x32_bf16(a, b, acc[cc], 0, 0, 0);
      }
    }
  }
  unsigned int m1p[4][2];
#pragma unroll
  for (int cc = 0; cc < 4; ++cc) {
    int ct = cg * 4 + cc;
    const float4 b1 = *(const float4*)(nb1 + ct * 16 + 4 * q);
    m1p[cc][0] = pack2bf(fsilu(acc[cc][0] + b1.x), fsilu(acc[cc][1] + b1.y));
    m1p[cc][1] = pack2bf(fsilu(acc[cc][2] + b1.z), fsilu(acc[cc][3] + b1.w));
  }
  __syncthreads();
#pragma unroll
  for (int cc = 0; cc < 4; ++cc) {
    int ct = cg * 4 + cc;
    *(uint2*)(Smem + erow * 136 + ct * 16 + 4 * q) = *(uint2*)m1p[cc];
  }
  __syncthreads();

  floatx4 acc2[4];
#pragma unroll
  for (int cc = 0; cc < 4; ++cc) acc2[cc] = (floatx4){0.f, 0.f, 0.f, 0.f};
  {
    const short* Brow = Smem + erow * 136 + q * 8;
    const short8* A = (const short8*)N2f;
#pragma unroll
    for (int kt = 0; kt < 4; ++kt) {
      short8 b = *(const short8*)(Brow + kt * 32);
#pragma unroll
      for (int cc = 0; cc < 4; ++cc) {
        short8 a = A[kt * 512 + (cg * 4 + cc) * 64 + lane];
        acc2[cc] = __builtin_amdgcn_mfma_f32_16x16x32_bf16(a, b, acc2[cc], 0, 0, 0);
      }
    }
  }
  const int node = n0 + erow;
  if (node < N_NODES) {
#pragma unroll
    for (int cc = 0; cc < 4; ++cc) {
      int col = (cg * 4 + cc) * 16 + 4 * q;
      const float4 b2 = *(const float4*)(nb2 + col);
      const float4 hr = *(const float4*)(h + (size_t)node * 128 + col);
      float4 o;
      o.x = acc2[cc][0] + b2.x + hr.x;
      o.y = acc2[cc][1] + b2.y + hr.y;
      o.z = acc2[cc][2] + b2.z + hr.z;
      o.w = acc2[cc][3] + b2.w + hr.w;
      *(float4*)(out + (size_t)node * 128 + col) = o;
    }
  }
}

extern "C" void kernel_launch(void* const* d_in, const int* in_sizes, int n_in,
                              void* d_out, int out_size, void* d_ws, size_t ws_size,
                              hipStream_t stream) {
  (void)in_sizes; (void)n_in; (void)out_size; (void)ws_size;
  const float* h   = (const float*)d_in[0];
  const int*   idx = (const int*)d_in[1];
  const float* eW1 = (const float*)d_in[2];
  const float* eb1 = (const float*)d_in[3];
  const float* eW2 = (const float*)d_in[4];
  const float* eb2 = (const float*)d_in[5];
  const float* aW  = (const float*)d_in[6];
  const float* ab  = (const float*)d_in[7];
  const float* nW1 = (const float*)d_in[8];
  const float* nb1 = (const float*)d_in[9];
  const float* nW2 = (const float*)d_in[10];
  const float* nb2 = (const float*)d_in[11];
  float* out = (float*)d_out;

  // ws layout
  char* wp = (char*)d_ws;
  unsigned short* agg = (unsigned short*)wp;  wp += (size_t)N_NODES * 128 * 2;  // 12.8 MB
  short* h_bf = (short*)wp;                   wp += (size_t)N_NODES * 128 * 2;  // 12.8 MB
  short* Rb  = (short*)wp;                    wp += (size_t)N_NODES * 128 * 2;  // 12.8 MB
  short* W1f = (short*)wp;                    wp += 32768 * 2;
  short* W2f = (short*)wp;                    wp += 16384 * 2;
  short* N1f = (short*)wp;                    wp += 32768 * 2;
  short* N2f = (short*)wp;                    wp += 16384 * 2;
  int* cnt  = (int*)wp;                       wp += N_NODES * 4;
  int* ctmp = (int*)wp;                       wp += N_NODES * 4;
  int* rank = (int*)wp;                       wp += (size_t)N_EDGES * 4;
  int2* sedge = (int2*)wp;                    wp += (size_t)N_EDGES * 8;
  int* bsum = (int*)wp;                       wp += 128 * 4;
  int* boff = (int*)wp;                       wp += 128 * 4;

  hipMemsetAsync(agg, 0, (size_t)N_NODES * 128 * 2, stream);
  hipMemsetAsync(cnt, 0, N_NODES * 4, stream);
  prep_weights<<<48, 256, 0, stream>>>(eW1, eW2, nW1, nW2, W1f, W2f, N1f, N2f);
  prep_hR<<<(N_NODES + 63) / 64, 512, 0, stream>>>(h, W1f, h_bf, Rb);
  hist_kernel<<<N_EDGES / 256, 256, 0, stream>>>(idx, cnt, rank);
  scan1<<<98, 512, 0, stream>>>(cnt, bsum);
  scan2<<<1, 128, 0, stream>>>(bsum, boff);
  scan3<<<98, 512, 0, stream>>>(cnt, boff, ctmp);
  place_kernel<<<N_EDGES / 256, 256, 0, stream>>>(idx, ctmp, rank, sedge);
  edge_kernel<<<N_EDGES / 64, 512, 0, stream>>>(h_bf, Rb, sedge, W1f, W2f,
                                                eb1, eb2, aW, ab, agg);
  node_kernel<<<(N_NODES + 63) / 64, 512, 0, stream>>>(h, h_bf, (const short*)agg,
                                                       N1f, N2f, nb1, nb2, out);
}

// Round 9
// 376.812 us; speedup vs baseline: 3.0615x; 1.0810x over previous
//
#include <hip/hip_runtime.h>

#define N_NODES 50000
#define N_EDGES 800000

typedef __attribute__((ext_vector_type(8))) short short8;
typedef __attribute__((ext_vector_type(4))) float floatx4;

__device__ __forceinline__ short f2bf(float f) {
  unsigned int u = __builtin_bit_cast(unsigned int, f);
  unsigned int r = (u + 0x7FFFu + ((u >> 16) & 1u)) >> 16;
  return (short)r;
}
// pack two f32 -> packed bf16 dword, round-to-nearest (+0x8000): 5 VALU
__device__ __forceinline__ unsigned int pack2bf(float a, float b) {
  unsigned int ua = __builtin_bit_cast(unsigned int, a);
  unsigned int ub = __builtin_bit_cast(unsigned int, b);
  return ((ua + 0x8000u) >> 16) | ((ub + 0x8000u) & 0xFFFF0000u);
}
__device__ __forceinline__ float bflo2f(unsigned int u) {
  return __builtin_bit_cast(float, u << 16);
}
__device__ __forceinline__ float bfhi2f(unsigned int u) {
  return __builtin_bit_cast(float, u & 0xFFFF0000u);
}
__device__ __forceinline__ float fsilu(float v) {
  float e = __builtin_amdgcn_exp2f(v * -1.442695041f);
  return v * __builtin_amdgcn_rcpf(1.f + e);
}

// f32 weights [K,128] -> bf16 MFMA frag order (doubles as A-frag of W^T)
__global__ void prep_weights(const float* __restrict__ eW1, const float* __restrict__ eW2,
                             const float* __restrict__ nW1, const float* __restrict__ nW2,
                             short* __restrict__ W1f, short* __restrict__ W2f,
                             short* __restrict__ N1f, short* __restrict__ N2f) {
  int id = blockIdx.x * 256 + threadIdx.x;   // 0..12287
  const float* src; short* dst; int ch;
  if (id < 4096)       { src = eW1; dst = W1f; ch = id; }
  else if (id < 6144)  { src = eW2; dst = W2f; ch = id - 4096; }
  else if (id < 10240) { src = nW1; dst = N1f; ch = id - 6144; }
  else                 { src = nW2; dst = N2f; ch = id - 10240; }
  int kt = ch >> 9;
  int c  = (ch >> 6) & 7;
  int l  = ch & 63;
  int q = l >> 4, n = l & 15;
  int k0 = kt * 32 + q * 8;
  int col = c * 16 + n;
  short tmp[8];
#pragma unroll
  for (int j = 0; j < 8; ++j) tmp[j] = f2bf(src[(k0 + j) * 128 + col]);
#pragma unroll
  for (int j = 0; j < 8; ++j) dst[ch * 8 + j] = tmp[j];
}

// Per-node layer-1 split: R' = h @ eW1_top + eb1,  S = h @ eW1_bot (both bf16).
// Transposed GEMM, 64 nodes/block, 512 threads.
__global__ void __launch_bounds__(512, 6) prep_hR(
    const float* __restrict__ h, const short* __restrict__ W1f,
    const float* __restrict__ eb1,
    short* __restrict__ Rb, short* __restrict__ Sb) {
  __shared__ __align__(16) short Z[64 * 136];
  const int tid = threadIdx.x;
  const int n0 = blockIdx.x * 64;
#pragma unroll
  for (int i = 0; i < 4; ++i) {
    int id = i * 512 + tid;
    int r = id >> 5, cq = id & 31;
    int rg = n0 + r; if (rg >= N_NODES) rg = N_NODES - 1;
    float4 v = *(const float4*)(h + (size_t)rg * 128 + cq * 4);
    uint2 s;
    s.x = pack2bf(v.x, v.y);
    s.y = pack2bf(v.z, v.w);
    *(uint2*)(Z + r * 136 + cq * 4) = s;
  }
  __syncthreads();
  const int w = tid >> 6, lane = tid & 63, q = lane >> 4, n = lane & 15;
  const int et = w & 3, cg = w >> 2;
  const int erow = et * 16 + n;
  floatx4 accR[4], accS[4];
#pragma unroll
  for (int cc = 0; cc < 4; ++cc) {
    accR[cc] = (floatx4){0.f, 0.f, 0.f, 0.f};
    accS[cc] = (floatx4){0.f, 0.f, 0.f, 0.f};
  }
  const short* Brow = Z + erow * 136 + q * 8;
  const short8* A = (const short8*)W1f;
#pragma unroll
  for (int kt = 0; kt < 4; ++kt) {
    short8 b = *(const short8*)(Brow + kt * 32);
#pragma unroll
    for (int cc = 0; cc < 4; ++cc) {
      short8 aT = A[kt * 512 + (cg * 4 + cc) * 64 + lane];          // top half
      accR[cc] = __builtin_amdgcn_mfma_f32_16x16x32_bf16(aT, b, accR[cc], 0, 0, 0);
      short8 aB = A[(kt + 4) * 512 + (cg * 4 + cc) * 64 + lane];    // bottom half
      accS[cc] = __builtin_amdgcn_mfma_f32_16x16x32_bf16(aB, b, accS[cc], 0, 0, 0);
    }
  }
  const int node = n0 + erow;
  if (node < N_NODES) {
#pragma unroll
    for (int cc = 0; cc < 4; ++cc) {
      int col = (cg * 4 + cc) * 16 + 4 * q;
      const float4 b1 = *(const float4*)(eb1 + col);
      uint2 ur, us;
      ur.x = pack2bf(accR[cc][0] + b1.x, accR[cc][1] + b1.y);
      ur.y = pack2bf(accR[cc][2] + b1.z, accR[cc][3] + b1.w);
      us.x = pack2bf(accS[cc][0], accS[cc][1]);
      us.y = pack2bf(accS[cc][2], accS[cc][3]);
      *(uint2*)(Rb + (size_t)node * 128 + col) = ur;
      *(uint2*)(Sb + (size_t)node * 128 + col) = us;
    }
  }
}

// ---- CSR build: histogram of destination rows; atomic return = edge's rank
__global__ void hist_kernel(const int* __restrict__ idx, int* __restrict__ cnt,
                            int* __restrict__ rank) {
  int gid = blockIdx.x * 256 + threadIdx.x;
  rank[gid] = atomicAdd(&cnt[idx[gid]], 1);
}

// two-level exclusive scan of cnt[50000] -> ctmp
__global__ void scan1(const int* __restrict__ cnt, int* __restrict__ bsum) {
  const int t = threadIdx.x;
  int i = blockIdx.x * 512 + t;
  int v = (i < N_NODES) ? cnt[i] : 0;
#pragma unroll
  for (int o = 1; o < 64; o <<= 1) v += __shfl_xor(v, o, 64);
  __shared__ int ws_[8];
  if ((t & 63) == 0) ws_[t >> 6] = v;
  __syncthreads();
  if (t == 0) {
    int s = 0;
#pragma unroll
    for (int k = 0; k < 8; ++k) s += ws_[k];
    bsum[blockIdx.x] = s;
  }
}

__global__ void scan2(const int* __restrict__ bsum, int* __restrict__ boff) {
  const int t = threadIdx.x;   // 128 threads
  int v = (t < 98) ? bsum[t] : 0;
  int incl = v;
  const int lane = t & 63;
#pragma unroll
  for (int o = 1; o < 64; o <<= 1) {
    int tmp = __shfl_up(incl, o, 64);
    if (lane >= o) incl += tmp;
  }
  __shared__ int s0;
  if (t == 63) s0 = incl;
  __syncthreads();
  if (t >= 64) incl += s0;
  boff[t] = incl - v;
}

__global__ void scan3(const int* __restrict__ cnt, const int* __restrict__ boff,
                      int* __restrict__ ctmp) {
  const int t = threadIdx.x;
  const int i = blockIdx.x * 512 + t;
  int v = (i < N_NODES) ? cnt[i] : 0;
  int incl = v;
  const int lane = t & 63;
#pragma unroll
  for (int o = 1; o < 64; o <<= 1) {
    int tmp = __shfl_up(incl, o, 64);
    if (lane >= o) incl += tmp;
  }
  __shared__ int wsum[8];
  if (lane == 63) wsum[t >> 6] = incl;
  __syncthreads();
  if (t == 0) {
    int run = 0;
#pragma unroll
    for (int k = 0; k < 8; ++k) { int x = wsum[k]; wsum[k] = run; run += x; }
  }
  __syncthreads();
  if (i < N_NODES) ctmp[i] = incl - v + wsum[t >> 6] + boff[blockIdx.x];
}

// place edges into sorted order: p = row_base + precomputed rank (NO atomics)
__global__ void place_kernel(const int* __restrict__ idx, const int* __restrict__ ctmp,
                             const int* __restrict__ rank, int2* __restrict__ sedge) {
  int gid = blockIdx.x * 256 + threadIdx.x;
  int r = idx[gid];
  int c = idx[N_EDGES + gid];
  int p = ctmp[r] + rank[gid];
  sedge[p] = make_int2(r, c);
}

// Edge kernel: layer-1 fully elementwise (m1 = silu(R'[row] + S[col])); layer-2
// transposed MFMA; segmented shfl scan (exec-branch) + tail pk-bf16 atomics.
// 64 sorted edges/block, 512 threads. Wave w: et=w&3, cg=w>>2. Lane(q,n):
// edge erow=et*16+n, channels (cg*4+cc)*16+4q+j.
__global__ void __launch_bounds__(512, 8) edge_kernel(
    const short* __restrict__ Rb, const short* __restrict__ Sb,
    const int2* __restrict__ sedge, const short* __restrict__ W2f,
    const float* __restrict__ eb2, const float* __restrict__ aW,
    const float* __restrict__ ab, unsigned short* __restrict__ agg) {
  __shared__ __align__(16) short M1[64 * 136];
  __shared__ float patt[64][2];
  const int tid = threadIdx.x;
  const int e0 = blockIdx.x * 64;
  const int w = tid >> 6, lane = tid & 63, q = lane >> 4, n = lane & 15;
  const int et = w & 3, cg = w >> 2;
  const int erow = et * 16 + n;
  const int2 ed = sedge[e0 + erow];
  const int myrow = ed.x;

  // ---- layer 1 elementwise: m1 = silu(R'[row] + S[col])
  {
    const short* Rrow = Rb + (size_t)myrow * 128;
    const short* Srow = Sb + (size_t)ed.y * 128;
#pragma unroll
    for (int cc = 0; cc < 4; ++cc) {
      int off = (cg * 4 + cc) * 16 + 4 * q;
      uint2 ur = *(const uint2*)(Rrow + off);
      uint2 us = *(const uint2*)(Srow + off);
      float v0 = bflo2f(ur.x) + bflo2f(us.x);
      float v1 = bfhi2f(ur.x) + bfhi2f(us.x);
      float v2 = bflo2f(ur.y) + bflo2f(us.y);
      float v3 = bfhi2f(ur.y) + bfhi2f(us.y);
      uint2 u;
      u.x = pack2bf(fsilu(v0), fsilu(v1));
      u.y = pack2bf(fsilu(v2), fsilu(v3));
      *(uint2*)(M1 + erow * 136 + off) = u;
    }
  }
  __syncthreads();

  // ---- layer 2 (transposed): C^T = W2^T @ M1^T
  floatx4 acc2[4];
#pragma unroll
  for (int cc = 0; cc < 4; ++cc) acc2[cc] = (floatx4){0.f, 0.f, 0.f, 0.f};
  {
    const short* Brow = M1 + erow * 136 + q * 8;
    const short8* A = (const short8*)W2f;
#pragma unroll
    for (int kt = 0; kt < 4; ++kt) {
      short8 b = *(const short8*)(Brow + kt * 32);
#pragma unroll
      for (int cc = 0; cc < 4; ++cc) {
        short8 a = A[kt * 512 + (cg * 4 + cc) * 64 + lane];
        acc2[cc] = __builtin_amdgcn_mfma_f32_16x16x32_bf16(a, b, acc2[cc], 0, 0, 0);
      }
    }
  }
  // ---- silu + attention partial dot
  float sil[4][4];
  float p = 0.f;
#pragma unroll
  for (int cc = 0; cc < 4; ++cc) {
    int ct = cg * 4 + cc;
    const float4 b2 = *(const float4*)(eb2 + ct * 16 + 4 * q);
    const float4 av = *(const float4*)(aW + ct * 16 + 4 * q);
#pragma unroll
    for (int j = 0; j < 4; ++j) {
      float v = fsilu(acc2[cc][j] + ((const float*)&b2)[j]);
      sil[cc][j] = v;
      p += v * ((const float*)&av)[j];
    }
  }
  p += __shfl_xor(p, 16, 64);
  p += __shfl_xor(p, 32, 64);
  if (q == 0) patt[erow][cg] = p;
  __syncthreads();

  float s = patt[erow][0] + patt[erow][1] + ab[0];
  float att = 0.01f * __builtin_amdgcn_rcpf(1.f + __builtin_amdgcn_exp2f(-1.442695041f * s));
#pragma unroll
  for (int cc = 0; cc < 4; ++cc)
#pragma unroll
    for (int j = 0; j < 4; ++j) sil[cc][j] *= att;

  // ---- segmented reduction over sorted-row runs along n (16 edges/tile)
  const int prevrow = __shfl_up(myrow, 1, 64);
  const bool head = (n == 0) || (myrow != prevrow);
  const unsigned long long m = __ballot(head);
  const unsigned long long lower = (lane == 63) ? ~0ull : ((2ull << lane) - 1ull);
  const int headpos = 63 - __builtin_clzll(m & lower);
  const int hd = lane - headpos;
  const bool tail = (n == 15) || (((m >> (lane + 1)) & 1ull) != 0);
#pragma unroll
  for (int d = 1; d < 16; d <<= 1) {
    float t[4][4];
#pragma unroll
    for (int cc = 0; cc < 4; ++cc)
#pragma unroll
      for (int j = 0; j < 4; ++j)
        t[cc][j] = __shfl_up(sil[cc][j], d, 64);
    if (d <= hd) {
#pragma unroll
      for (int cc = 0; cc < 4; ++cc)
#pragma unroll
        for (int j = 0; j < 4; ++j)
          sil[cc][j] += t[cc][j];
    }
  }
  // ---- run tails flush run totals: 8 pk-bf16 atomics per tail lane
  if (tail) {
    unsigned short* base = agg + (size_t)myrow * 128;
#pragma unroll
    for (int cc = 0; cc < 4; ++cc) {
      int colb = (cg * 4 + cc) * 16 + 4 * q;
      unsigned int u0 = pack2bf(sil[cc][0], sil[cc][1]);
      unsigned int u1 = pack2bf(sil[cc][2], sil[cc][3]);
      asm volatile("global_atomic_pk_add_bf16 %0, %1, off" :: "v"(base + colb), "v"(u0) : "memory");
      asm volatile("global_atomic_pk_add_bf16 %0, %1, off" :: "v"(base + colb + 2), "v"(u1) : "memory");
    }
  }
  asm volatile("s_waitcnt vmcnt(0)" ::: "memory");   // drain untracked asm atomics
}

// Node kernel (transposed, 512 threads): 64 nodes/block, 8 waves.
__global__ void __launch_bounds__(512, 6) node_kernel(
    const float* __restrict__ h, const short* __restrict__ agg,
    const short* __restrict__ N1f, const short* __restrict__ N2f,
    const float* __restrict__ nb1, const float* __restrict__ nb2,
    float* __restrict__ out) {
  __shared__ __align__(16) short Smem[16896];   // Z[64][264] overlaid by M1[64][136]
  const int tid = threadIdx.x;
  const int n0 = blockIdx.x * 64;
#pragma unroll
  for (int i = 0; i < 4; ++i) {
    int id = i * 512 + tid;
    int r = id >> 5, ch = id & 31;
    int rg = n0 + r;
    if (rg >= N_NODES) rg = N_NODES - 1;
    if (ch < 16) {
      const float* hp = h + (size_t)rg * 128 + ch * 8;
      float4 a = *(const float4*)hp;
      float4 b = *(const float4*)(hp + 4);
      uint4 sv;
      sv.x = pack2bf(a.x, a.y);
      sv.y = pack2bf(a.z, a.w);
      sv.z = pack2bf(b.x, b.y);
      sv.w = pack2bf(b.z, b.w);
      *(uint4*)(Smem + r * 264 + ch * 8) = sv;
    } else {
      *(uint4*)(Smem + r * 264 + ch * 8) =
          *(const uint4*)(agg + (size_t)rg * 128 + (ch - 16) * 8);
    }
  }
  __syncthreads();
  const int w = tid >> 6, lane = tid & 63, q = lane >> 4, n = lane & 15;
  const int et = w & 3, cg = w >> 2;
  const int erow = et * 16 + n;

  floatx4 acc[4];
#pragma unroll
  for (int cc = 0; cc < 4; ++cc) acc[cc] = (floatx4){0.f, 0.f, 0.f, 0.f};
  {
    const short* Brow = Smem + erow * 264 + q * 8;
    const short8* A = (const short8*)N1f;
#pragma unroll
    for (int kt = 0; kt < 8; ++kt) {
      short8 b = *(const short8*)(Brow + kt * 32);
#pragma unroll
      for (int cc = 0; cc < 4; ++cc) {
        short8 a = A[kt * 512 + (cg * 4 + cc) * 64 + lane];
        acc[cc] = __builtin_amdgcn_mfma_f32_16x16x32_bf16(a, b, acc[cc], 0, 0, 0);
      }
    }
  }
  unsigned int m1p[4][2];
#pragma unroll
  for (int cc = 0; cc < 4; ++cc) {
    int ct = cg * 4 + cc;
    const float4 b1 = *(const float4*)(nb1 + ct * 16 + 4 * q);
    m1p[cc][0] = pack2bf(fsilu(acc[cc][0] + b1.x), fsilu(acc[cc][1] + b1.y));
    m1p[cc][1] = pack2bf(fsilu(acc[cc][2] + b1.z), fsilu(acc[cc][3] + b1.w));
  }
  __syncthreads();
#pragma unroll
  for (int cc = 0; cc < 4; ++cc) {
    int ct = cg * 4 + cc;
    *(uint2*)(Smem + erow * 136 + ct * 16 + 4 * q) = *(uint2*)m1p[cc];
  }
  __syncthreads();

  floatx4 acc2[4];
#pragma unroll
  for (int cc = 0; cc < 4; ++cc) acc2[cc] = (floatx4){0.f, 0.f, 0.f, 0.f};
  {
    const short* Brow = Smem + erow * 136 + q * 8;
    const short8* A = (const short8*)N2f;
#pragma unroll
    for (int kt = 0; kt < 4; ++kt) {
      short8 b = *(const short8*)(Brow + kt * 32);
#pragma unroll
      for (int cc = 0; cc < 4; ++cc) {
        short8 a = A[kt * 512 + (cg * 4 + cc) * 64 + lane];
        acc2[cc] = __builtin_amdgcn_mfma_f32_16x16x32_bf16(a, b, acc2[cc], 0, 0, 0);
      }
    }
  }
  const int node = n0 + erow;
  if (node < N_NODES) {
#pragma unroll
    for (int cc = 0; cc < 4; ++cc) {
      int col = (cg * 4 + cc) * 16 + 4 * q;
      const float4 b2 = *(const float4*)(nb2 + col);
      const float4 hr = *(const float4*)(h + (size_t)node * 128 + col);
      float4 o;
      o.x = acc2[cc][0] + b2.x + hr.x;
      o.y = acc2[cc][1] + b2.y + hr.y;
      o.z = acc2[cc][2] + b2.z + hr.z;
      o.w = acc2[cc][3] + b2.w + hr.w;
      *(float4*)(out + (size_t)node * 128 + col) = o;
    }
  }
}

extern "C" void kernel_launch(void* const* d_in, const int* in_sizes, int n_in,
                              void* d_out, int out_size, void* d_ws, size_t ws_size,
                              hipStream_t stream) {
  (void)in_sizes; (void)n_in; (void)out_size; (void)ws_size;
  const float* h   = (const float*)d_in[0];
  const int*   idx = (const int*)d_in[1];
  const float* eW1 = (const float*)d_in[2];
  const float* eb1 = (const float*)d_in[3];
  const float* eW2 = (const float*)d_in[4];
  const float* eb2 = (const float*)d_in[5];
  const float* aW  = (const float*)d_in[6];
  const float* ab  = (const float*)d_in[7];
  const float* nW1 = (const float*)d_in[8];
  const float* nb1 = (const float*)d_in[9];
  const float* nW2 = (const float*)d_in[10];
  const float* nb2 = (const float*)d_in[11];
  float* out = (float*)d_out;

  // ws layout
  char* wp = (char*)d_ws;
  unsigned short* agg = (unsigned short*)wp;  wp += (size_t)N_NODES * 128 * 2;  // 12.8 MB
  short* Rb  = (short*)wp;                    wp += (size_t)N_NODES * 128 * 2;  // 12.8 MB
  short* Sb  = (short*)wp;                    wp += (size_t)N_NODES * 128 * 2;  // 12.8 MB
  short* W1f = (short*)wp;                    wp += 32768 * 2;
  short* W2f = (short*)wp;                    wp += 16384 * 2;
  short* N1f = (short*)wp;                    wp += 32768 * 2;
  short* N2f = (short*)wp;                    wp += 16384 * 2;
  int* cnt  = (int*)wp;                       wp += N_NODES * 4;
  int* ctmp = (int*)wp;                       wp += N_NODES * 4;
  int* rank = (int*)wp;                       wp += (size_t)N_EDGES * 4;
  int2* sedge = (int2*)wp;                    wp += (size_t)N_EDGES * 8;
  int* bsum = (int*)wp;                       wp += 128 * 4;
  int* boff = (int*)wp;                       wp += 128 * 4;

  hipMemsetAsync(agg, 0, (size_t)N_NODES * 128 * 2, stream);
  hipMemsetAsync(cnt, 0, N_NODES * 4, stream);
  prep_weights<<<48, 256, 0, stream>>>(eW1, eW2, nW1, nW2, W1f, W2f, N1f, N2f);
  prep_hR<<<(N_NODES + 63) / 64, 512, 0, stream>>>(h, W1f, eb1, Rb, Sb);
  hist_kernel<<<N_EDGES / 256, 256, 0, stream>>>(idx, cnt, rank);
  scan1<<<98, 512, 0, stream>>>(cnt, bsum);
  scan2<<<1, 128, 0, stream>>>(bsum, boff);
  scan3<<<98, 512, 0, stream>>>(cnt, boff, ctmp);
  place_kernel<<<N_EDGES / 256, 256, 0, stream>>>(idx, ctmp, rank, sedge);
  edge_kernel<<<N_EDGES / 64, 512, 0, stream>>>(Rb, Sb, sedge, W2f,
                                                eb2, aW, ab, agg);
  node_kernel<<<(N_NODES + 63) / 64, 512, 0, stream>>>(h, (const short*)agg,
                                                       N1f, N2f, nb1, nb2, out);
}